// Round 6
// baseline (2741.530 us; speedup 1.0000x reference)
//
#include <hip/hip_runtime.h>

#define NN    32768
#define NACT  28672
#define NPAD  4096
#define NEDGE 229376
#define NLAY  8

// packed weight layout: per layer, W1 plane (f16) then W2 plane (f16, (w-w1)*2048)
#define WOFF_T0 0        // edge W1ext : KT=4 NT=9
#define WOFF_T1 18432    // mlp1 W1    : KT=2 NT=8
#define WOFF_T2 26624    // mlp1 W2ext : KT=4 NT=5
#define WOFF_T3 36864    // node W1ext : KT=4 NT=12
#define WOFF_T4 61440    // node W2    : KT=4 NT=4
#define WLO     69632
#define WLAYER  139264

typedef __attribute__((ext_vector_type(8))) short s16x8;
typedef __attribute__((ext_vector_type(8))) _Float16 f16x8;
typedef __attribute__((ext_vector_type(4))) float f32x4;

#define MFMAH(a,b,c) __builtin_amdgcn_mfma_f32_16x16x32_f16((a),(b),(c),0,0,0)
#define INV2048 4.8828125e-4f

__device__ __forceinline__ unsigned short f2h(float f){
  union { _Float16 h; unsigned short u; } v; v.h = (_Float16)f; return v.u;
}
__device__ __forceinline__ float h2f(unsigned short u){
  union { unsigned short u; _Float16 h; } v; v.u = u; return (float)v.h;
}
// scaled f16 split: a = h + r/2048, |err| ~ 2^-24|a|; denormal-guarded
__device__ __forceinline__ void split16(float a, unsigned short& h, unsigned short& r){
  float hf = 0.f; unsigned short hu = 0;
  if (__builtin_fabsf(a) >= 6.1035156e-5f){ hu = f2h(a); hf = h2f(hu); }
  h = hu;
  r = f2h((a - hf) * 2048.0f);
}
__device__ __forceinline__ void split8v(const float* v, s16x8& h, s16x8& r){
  #pragma unroll
  for (int i=0;i<8;++i){
    unsigned short hh, rr; split16(v[i], hh, rr);
    h[i] = (short)hh; r[i] = (short)rr;
  }
}

// ---------------- weight packing (f16 W1 + scaled-f16 W2 planes) ----------------
__global__ void k_pack(const float* __restrict__ ew1, const float* __restrict__ eresw,
                       const float* __restrict__ n1w1, const float* __restrict__ n1w2,
                       const float* __restrict__ n2w1, const float* __restrict__ n2resw,
                       const float* __restrict__ n2w2,
                       unsigned short* __restrict__ wfrag){
  const int l = blockIdx.y, T = blockIdx.z;
  int KT, NT, off;
  if (T==0){ KT=4; NT=9;  off=WOFF_T0; }
  else if (T==1){ KT=2; NT=8;  off=WOFF_T1; }
  else if (T==2){ KT=4; NT=5;  off=WOFF_T2; }
  else if (T==3){ KT=4; NT=12; off=WOFF_T3; }
  else          { KT=4; NT=4;  off=WOFF_T4; }
  const int f = blockIdx.x*256 + threadIdx.x;
  if (f >= KT*NT*64) return;
  const int lane = f & 63;
  const int fn = f >> 6;
  const int nt = fn % NT, ks = fn / NT;
  const int n  = nt*16 + (lane & 15);
  const int kb = ks*32 + (lane >> 4)*8;
  s16x8 vh, vl;
  #pragma unroll
  for (int i=0;i<8;++i){
    const int k = kb + i;
    float w = 0.f;
    if (T==0){
      if (n < 128)      w = ew1[((size_t)l*130 + k)*128 + n];
      else if (n < 130) w = eresw[((size_t)l*130 + k)*2 + (n-128)];
    } else if (T==1){
      w = n1w1[((size_t)l*66 + k)*128 + n];
    } else if (T==2){
      if (n < 66) w = n1w2[((size_t)l*128 + k)*66 + n];
    } else if (T==3){
      if (n < 128) w = n2w1[((size_t)l*130 + k)*128 + n];
      else         w = n2resw[((size_t)l*130 + k)*64 + (n-128)];
    } else {
      w = n2w2[((size_t)l*128 + k)*64 + n];
    }
    unsigned short hh, rr; split16(w, hh, rr);
    vh[i] = (short)hh; vl[i] = (short)rr;
  }
  *(s16x8*)(wfrag + (size_t)l*WLAYER + off + (size_t)f*8) = vh;
  *(s16x8*)(wfrag + (size_t)l*WLAYER + off + WLO + (size_t)f*8) = vl;
}

// ---------------- init / degree / sort ----------------
__global__ void k_init(const float* __restrict__ x, const float* __restrict__ ea,
                       float* __restrict__ nodes, float* __restrict__ edges,
                       int* __restrict__ cnt){
  const int i = blockIdx.x*256 + threadIdx.x;   // grid = exactly NN*64
  nodes[i] = (i >= NPAD*64) ? x[i - NPAD*64] : 0.f;
  if (i < NEDGE*2) edges[i] = ea[i];
  if (i < NN) cnt[i] = 0;
}

__global__ void k_count(const int* __restrict__ ei, int* __restrict__ cnt){
  const int e = blockIdx.x*256 + threadIdx.x;
  if (e < NEDGE) atomicAdd(&cnt[ei[NEDGE + e]], 1);
}

__global__ void k_inv(const int* __restrict__ cnt, float* __restrict__ invc,
                      int* __restrict__ fill){
  const int n = blockIdx.x*256 + threadIdx.x;
  if (n < NN){ invc[n] = 1.0f / (float)max(cnt[n], 1); fill[n] = 0; }
}

__global__ void k_scan(const int* __restrict__ cnt, int* __restrict__ row_start){
  __shared__ int part[256];
  const int t = threadIdx.x;
  int s = 0;
  for (int i=0;i<128;++i) s += cnt[t*128+i];
  part[t] = s;
  __syncthreads();
  if (t == 0){
    int run = 0;
    for (int i=0;i<256;++i){ const int v = part[i]; part[i] = run; run += v; }
  }
  __syncthreads();
  int base = part[t];
  for (int i=0;i<128;++i){ row_start[t*128+i] = base; base += cnt[t*128+i]; }
  if (t == 255) row_start[NN] = base;
}

__global__ void k_place(const int* __restrict__ ei, const int* __restrict__ row_start,
                        int* __restrict__ fill, int* __restrict__ ssrc,
                        int* __restrict__ sdst, int* __restrict__ seid){
  const int e = blockIdx.x*256 + threadIdx.x;
  if (e >= NEDGE) return;
  const int d = ei[NEDGE + e];
  const int pos = row_start[d] + atomicAdd(&fill[d], 1);
  ssrc[pos] = ei[e];
  sdst[pos] = d;
  seid[pos] = e;
}

// deterministic within-bucket order: insertion sort by eid (deg ~7)
__global__ void k_sortb(const int* __restrict__ row_start,
                        int* __restrict__ seid, int* __restrict__ ssrc){
  const int n = blockIdx.x*256 + threadIdx.x;
  if (n >= NN) return;
  const int rs = row_start[n], re = row_start[n+1];
  for (int i = rs+1; i < re; ++i){
    const int e = seid[i], s = ssrc[i];
    int j = i-1;
    while (j >= rs && seid[j] > e){ seid[j+1]=seid[j]; ssrc[j+1]=ssrc[j]; --j; }
    seid[j+1] = e; ssrc[j+1] = s;
  }
}

__global__ void k_zero_agg(float* __restrict__ agg){
  const int i = blockIdx.x*256 + threadIdx.x;   // grid exactly NN*66
  agg[i] = 0.f;
}

// CSR aggregation: one wave per node, no atomics; eid-ascending order matches
// np.add.at; true fp32 division matches the reference's "/ cnt".
__global__ __launch_bounds__(256)
void k_agg(const float* __restrict__ medge, const int* __restrict__ row_start,
           const int* __restrict__ cnt, float* __restrict__ agg){
  const int n = blockIdx.x*4 + (threadIdx.x >> 6);
  const int lane = threadIdx.x & 63;
  const int rs = row_start[n], re = row_start[n+1];
  const float cf = (float)max(cnt[n], 1);
  float a = 0.f, b = 0.f;
  for (int r = rs; r < re; ++r){
    const float* mr = medge + (size_t)r*68;
    a = __fadd_rn(a, mr[lane]);
    if (lane < 2) b = __fadd_rn(b, mr[64 + lane]);
  }
  agg[(size_t)n*66 + lane] = a / cf;
  if (lane < 2) agg[(size_t)n*66 + 64 + lane] = b / cf;
}

// ---------------- fused edge kernel: EdgeModel + NodeModel.mlp_1 ----------------
__global__ __launch_bounds__(256,2)
void k_edge(const int* __restrict__ sidx, const int* __restrict__ didx,
            const int* __restrict__ eidx_arr,
            float* __restrict__ edges,
            const float* __restrict__ nodes,
            const unsigned short* __restrict__ wf,
            float* __restrict__ agg, float* __restrict__ medge,
            const float* __restrict__ eb1, const float* __restrict__ ew2,
            const float* __restrict__ eb2, const float* __restrict__ eresb,
            const float* __restrict__ elng, const float* __restrict__ elnb,
            const float* __restrict__ ew1_tail,   // e_w1 rows 128,129 (stride 128)
            const float* __restrict__ eresw_tail, // e_res_w rows 128,129 (stride 2)
            const float* __restrict__ n1w1_tail,  // n1_w1 rows 64,65 (stride 128)
            const float* __restrict__ n1b1, const float* __restrict__ n1b2,
            const float* __restrict__ n1lng, const float* __restrict__ n1lnb)
{
  __shared__ __align__(16) unsigned char sAh[128*128];  // src f16 hi
  __shared__ __align__(16) unsigned char sAl[128*128];  // src f16 scaled-res
  __shared__ __align__(16) unsigned char sBH[128*256];  // dst hi/res; later H2 (256B rows)
  __shared__ float sEold[128][2];
  __shared__ int   sCol[128];
  __shared__ int   sEid[128];

  const int tid = threadIdx.x;
  const int ebase = blockIdx.x * 128;

  { // staging (threads 0..127 src, 128..255 dst)
    const int r = tid & 127, h = tid >> 7;
    const int es = ebase + r;
    const int swz = (r & 7) << 4;
    if (h == 0){
      const int sn = sidx[es];
      const float4* sp = (const float4*)(nodes + (size_t)sn*64);
      #pragma unroll
      for (int c = 0; c < 8; ++c){
        const float4 f0 = sp[2*c], f1 = sp[2*c+1];
        float v[8] = {f0.x,f0.y,f0.z,f0.w,f1.x,f1.y,f1.z,f1.w};
        s16x8 hh, rr; split8v(v, hh, rr);
        const int o = r*128 + ((c*16) ^ swz);
        *(s16x8*)&sAh[o] = hh;
        *(s16x8*)&sAl[o] = rr;
      }
    } else {
      const int dn = didx[es];
      const int eid = eidx_arr ? eidx_arr[es] : es;
      const float4* dp = (const float4*)(nodes + (size_t)dn*64);
      #pragma unroll
      for (int c = 0; c < 8; ++c){
        const float4 f0 = dp[2*c], f1 = dp[2*c+1];
        float v[8] = {f0.x,f0.y,f0.z,f0.w,f1.x,f1.y,f1.z,f1.w};
        s16x8 hh, rr; split8v(v, hh, rr);
        const int o = r*128 + ((c*16) ^ swz);
        *(s16x8*)&sBH[o] = hh;
        *(s16x8*)&sBH[16384 + o] = rr;
      }
      const float2 ev = *(const float2*)(edges + (size_t)eid*2);
      sEold[r][0] = ev.x; sEold[r][1] = ev.y;
      sCol[r] = dn;
      sEid[r] = eid;
    }
  }
  __syncthreads();

  const int lane  = tid & 63;
  const int wv    = tid >> 6;
  const int colj  = lane & 15;
  const int g     = lane >> 4;
  const int rowA0 = wv*32 + colj;      // A-frag row (rb=0)
  const int mrow0 = wv*32 + g*4;       // C/D row base (add rb*16 + r)

  float e0r[2][4], e1r[2][4];
  #pragma unroll
  for (int rb=0; rb<2; ++rb)
    #pragma unroll
    for (int r=0; r<4; ++r){
      const int m = mrow0 + rb*16 + r;
      e0r[rb][r] = sEold[m][0]; e1r[rb][r] = sEold[m][1];
    }

  // ---- phase 1: Hext[128,144] = X[128,128] @ W1ext + e-cols fp32 rank-2 ----
  f32x4 acc1[9][2], accR[9][2];
  #pragma unroll
  for (int i=0;i<9;++i){
    acc1[i][0] = f32x4{0,0,0,0}; acc1[i][1] = f32x4{0,0,0,0};
    accR[i][0] = f32x4{0,0,0,0}; accR[i][1] = f32x4{0,0,0,0};
  }
  {
    #pragma unroll
    for (int ks = 0; ks < 4; ++ks){
      const int ch = (ks&1)*4 + g;
      const unsigned char* pH = (ks<2) ? sAh : sBH;
      const unsigned char* pL = (ks<2) ? sAl : (sBH + 16384);
      const int r1 = rowA0 + 16;
      const int o0 = rowA0*128 + ((ch*16) ^ ((rowA0&7)<<4));
      const int o1 = r1*128    + ((ch*16) ^ ((r1&7)<<4));
      const f16x8 ah0 = *(const f16x8*)&pH[o0];
      const f16x8 ah1 = *(const f16x8*)&pH[o1];
      const f16x8 ar0 = *(const f16x8*)&pL[o0];
      const f16x8 ar1 = *(const f16x8*)&pL[o1];
      const f16x8* bh = (const f16x8*)(wf + WOFF_T0) + (ks*9)*64 + lane;
      const f16x8* bl = (const f16x8*)(wf + WOFF_T0 + WLO) + (ks*9)*64 + lane;
      #pragma unroll
      for (int nt = 0; nt < 9; ++nt){
        const f16x8 b1 = bh[nt*64];
        const f16x8 b2 = bl[nt*64];
        acc1[nt][0] = MFMAH(ah0, b1, acc1[nt][0]);
        accR[nt][0] = MFMAH(ar0, b1, accR[nt][0]);
        accR[nt][0] = MFMAH(ah0, b2, accR[nt][0]);
        acc1[nt][1] = MFMAH(ah1, b1, acc1[nt][1]);
        accR[nt][1] = MFMAH(ar1, b1, accR[nt][1]);
        accR[nt][1] = MFMAH(ah1, b2, accR[nt][1]);
      }
    }
    #pragma unroll
    for (int nt=0; nt<9; ++nt)
      #pragma unroll
      for (int rb=0; rb<2; ++rb)
        #pragma unroll
        for (int r=0; r<4; ++r)
          acc1[nt][rb][r] += accR[nt][rb][r] * INV2048;
    #pragma unroll
    for (int nt=0; nt<9; ++nt){
      const int j = nt*16 + colj;
      float w0, w1;
      if (nt < 8){ w0 = ew1_tail[j]; w1 = ew1_tail[128 + j]; }
      else { w0 = (colj<2) ? eresw_tail[colj] : 0.f; w1 = (colj<2) ? eresw_tail[2+colj] : 0.f; }
      #pragma unroll
      for (int rb=0; rb<2; ++rb)
        #pragma unroll
        for (int r=0; r<4; ++r)
          acc1[nt][rb][r] += e0r[rb][r]*w0 + e1r[rb][r]*w1;
    }
  }

  // ---- phase 2: edge head (N=2) + LN(2) + residual ----
  float enew[2][4][2];
  {
    float2 w2v[8]; float b1v[8];
    #pragma unroll
    for (int nt=0; nt<8; ++nt){
      const int j = nt*16 + colj;
      w2v[nt] = *(const float2*)(ew2 + (size_t)j*2);
      b1v[nt] = eb1[j];
    }
    const float rb0 = eresb[0], rb1 = eresb[1];
    const float g0 = elng[0], g1 = elng[1], lb0 = elnb[0], lb1 = elnb[1];
    const float bb0 = eb2[0], bb1 = eb2[1];
    #pragma unroll
    for (int rb=0; rb<2; ++rb){
      #pragma unroll
      for (int r=0; r<4; ++r){
        float v0 = 0.f, v1 = 0.f;
        #pragma unroll
        for (int nt=0; nt<8; ++nt){
          const float h = fmaxf(acc1[nt][rb][r] + b1v[nt], 0.f);
          v0 = fmaf(h, w2v[nt].x, v0);
          v1 = fmaf(h, w2v[nt].y, v1);
        }
        const float resv = acc1[8][rb][r];
        if (colj == 0) v0 += resv + rb0;
        if (colj == 1) v1 += resv + rb1;
        #pragma unroll
        for (int mm=1; mm<16; mm<<=1){
          v0 += __shfl_xor(v0, mm, 64);
          v1 += __shfl_xor(v1, mm, 64);
        }
        v0 += bb0; v1 += bb1;
        // LayerNorm(2) with np-matching rounding
        const float m2 = __fmul_rn(__fadd_rn(v0, v1), 0.5f);
        const float d0 = __fsub_rn(v0, m2);
        const float d1 = __fsub_rn(v1, m2);
        const float var = __fmul_rn(__fadd_rn(__fmul_rn(d0,d0), __fmul_rn(d1,d1)), 0.5f);
        const float rstd = 1.0f / sqrtf(var + 1e-5f);
        const int m = mrow0 + rb*16 + r;
        const float e0 = __fadd_rn(__fadd_rn(__fmul_rn(__fmul_rn(d0, rstd), g0), lb0), e0r[rb][r]);
        const float e1 = __fadd_rn(__fadd_rn(__fmul_rn(__fmul_rn(d1, rstd), g1), lb1), e1r[rb][r]);
        enew[rb][r][0] = e0; enew[rb][r][1] = e1;
        if (colj == 0)
          *(float2*)(edges + (size_t)sEid[m]*2) = make_float2(e0, e1);
      }
    }
  }

  // ---- phase 3: H2[128,128] = src[128,64] @ n1_w1 (+ fp32 rank-2 for e) ----
  f32x4 acc2[8][2];
  {
    f32x4 acc2R[8][2];
    #pragma unroll
    for (int i=0;i<8;++i){
      acc2[i][0] = f32x4{0,0,0,0}; acc2[i][1] = f32x4{0,0,0,0};
      acc2R[i][0] = f32x4{0,0,0,0}; acc2R[i][1] = f32x4{0,0,0,0};
    }
    #pragma unroll
    for (int ks=0; ks<2; ++ks){
      const int ch = ks*4 + g;
      const int r1 = rowA0 + 16;
      const int o0 = rowA0*128 + ((ch*16) ^ ((rowA0&7)<<4));
      const int o1 = r1*128    + ((ch*16) ^ ((r1&7)<<4));
      const f16x8 ah0 = *(const f16x8*)&sAh[o0];
      const f16x8 ah1 = *(const f16x8*)&sAh[o1];
      const f16x8 ar0 = *(const f16x8*)&sAl[o0];
      const f16x8 ar1 = *(const f16x8*)&sAl[o1];
      const f16x8* bh = (const f16x8*)(wf + WOFF_T1) + (ks*8)*64 + lane;
      const f16x8* bl = (const f16x8*)(wf + WOFF_T1 + WLO) + (ks*8)*64 + lane;
      #pragma unroll
      for (int nt = 0; nt < 8; ++nt){
        const f16x8 b1 = bh[nt*64];
        const f16x8 b2 = bl[nt*64];
        acc2[nt][0]  = MFMAH(ah0, b1, acc2[nt][0]);
        acc2R[nt][0] = MFMAH(ar0, b1, acc2R[nt][0]);
        acc2R[nt][0] = MFMAH(ah0, b2, acc2R[nt][0]);
        acc2[nt][1]  = MFMAH(ah1, b1, acc2[nt][1]);
        acc2R[nt][1] = MFMAH(ar1, b1, acc2R[nt][1]);
        acc2R[nt][1] = MFMAH(ah1, b2, acc2R[nt][1]);
      }
    }
    #pragma unroll
    for (int nt=0; nt<8; ++nt)
      #pragma unroll
      for (int rb=0; rb<2; ++rb)
        #pragma unroll
        for (int r=0; r<4; ++r)
          acc2[nt][rb][r] += acc2R[nt][rb][r] * INV2048;
  }
  {
    #pragma unroll
    for (int nt=0; nt<8; ++nt){
      const int j = nt*16 + colj;
      const float w64 = n1w1_tail[j];
      const float w65 = n1w1_tail[128 + j];
      const float bb = n1b1[j];
      #pragma unroll
      for (int rb=0; rb<2; ++rb)
        #pragma unroll
        for (int r=0; r<4; ++r){
          float h = acc2[nt][rb][r] + enew[rb][r][0]*w64 + enew[rb][r][1]*w65 + bb;
          acc2[nt][rb][r] = fmaxf(h, 0.f);
        }
    }
  }

  __syncthreads();   // all phase-1 reads of sBH done before overwrite

  // ---- phase 4a: H2 hi (f16) -> LDS (256B rows over sBH) ----
  {
    #pragma unroll
    for (int nt=0; nt<8; ++nt){
      const int j = nt*16 + colj;
      const int co = (j>>3)<<4, wi = (j&7)*2;
      #pragma unroll
      for (int rb=0; rb<2; ++rb)
        #pragma unroll
        for (int r=0; r<4; ++r){
          const int m = mrow0 + rb*16 + r;
          unsigned short us, ur; split16(acc2[nt][rb][r], us, ur);
          *(unsigned short*)&sBH[m*256 + ((co ^ ((m&7)<<4)) + wi)] = us;
        }
    }
  }
  __syncthreads();

  // ---- phase 4b-hi: acc3 += H2hi@W1 ; acc3R += H2hi@W2 ----
  f32x4 acc3[5][2], acc3R[5][2];
  #pragma unroll
  for (int i=0;i<5;++i){
    acc3[i][0] = f32x4{0,0,0,0}; acc3[i][1] = f32x4{0,0,0,0};
    acc3R[i][0] = f32x4{0,0,0,0}; acc3R[i][1] = f32x4{0,0,0,0};
  }
  #pragma unroll
  for (int ks=0; ks<4; ++ks){
    const int ch = ks*4 + g;
    const int r1 = rowA0 + 16;
    const f16x8 a0 = *(const f16x8*)&sBH[rowA0*256 + ((ch*16) ^ ((rowA0&7)<<4))];
    const f16x8 a1 = *(const f16x8*)&sBH[r1*256    + ((ch*16) ^ ((r1&7)<<4))];
    const f16x8* bh = (const f16x8*)(wf + WOFF_T2) + (ks*5)*64 + lane;
    const f16x8* bl = (const f16x8*)(wf + WOFF_T2 + WLO) + (ks*5)*64 + lane;
    #pragma unroll
    for (int nt = 0; nt < 5; ++nt){
      const f16x8 b1 = bh[nt*64];
      const f16x8 b2 = bl[nt*64];
      acc3[nt][0]  = MFMAH(a0, b1, acc3[nt][0]);
      acc3R[nt][0] = MFMAH(a0, b2, acc3R[nt][0]);
      acc3[nt][1]  = MFMAH(a1, b1, acc3[nt][1]);
      acc3R[nt][1] = MFMAH(a1, b2, acc3R[nt][1]);
    }
  }
  __syncthreads();

  // ---- phase 4a': H2 scaled-residual -> LDS ----
  {
    #pragma unroll
    for (int nt=0; nt<8; ++nt){
      const int j = nt*16 + colj;
      const int co = (j>>3)<<4, wi = (j&7)*2;
      #pragma unroll
      for (int rb=0; rb<2; ++rb)
        #pragma unroll
        for (int r=0; r<4; ++r){
          const int m = mrow0 + rb*16 + r;
          unsigned short us, ur; split16(acc2[nt][rb][r], us, ur);
          *(unsigned short*)&sBH[m*256 + ((co ^ ((m&7)<<4)) + wi)] = ur;
        }
    }
  }
  __syncthreads();

  // ---- phase 4b-lo: acc3R += H2res@W1 ; fold ----
  #pragma unroll
  for (int ks=0; ks<4; ++ks){
    const int ch = ks*4 + g;
    const int r1 = rowA0 + 16;
    const f16x8 a0 = *(const f16x8*)&sBH[rowA0*256 + ((ch*16) ^ ((rowA0&7)<<4))];
    const f16x8 a1 = *(const f16x8*)&sBH[r1*256    + ((ch*16) ^ ((r1&7)<<4))];
    const f16x8* bh = (const f16x8*)(wf + WOFF_T2) + (ks*5)*64 + lane;
    #pragma unroll
    for (int nt = 0; nt < 5; ++nt){
      const f16x8 b1 = bh[nt*64];
      acc3R[nt][0] = MFMAH(a0, b1, acc3R[nt][0]);
      acc3R[nt][1] = MFMAH(a1, b1, acc3R[nt][1]);
    }
  }
  #pragma unroll
  for (int nt=0; nt<5; ++nt)
    #pragma unroll
    for (int rb=0; rb<2; ++rb)
      #pragma unroll
      for (int r=0; r<4; ++r)
        acc3[nt][rb][r] += acc3R[nt][rb][r] * INV2048;

  // ---- phase 4c: LN(66) two-pass (np-matching) + emit ----
  {
    float b2v[5], lgv[5], lbv[5];
    #pragma unroll
    for (int nt=0; nt<5; ++nt){
      const int j = nt*16 + colj;
      const bool ok = j < 66;
      b2v[nt] = ok ? n1b2[j]  : 0.f;
      lgv[nt] = ok ? n1lng[j] : 0.f;
      lbv[nt] = ok ? n1lnb[j] : 0.f;
    }
    #pragma unroll
    for (int rb=0; rb<2; ++rb){
      #pragma unroll
      for (int r=0; r<4; ++r){
        const int m = mrow0 + rb*16 + r;
        float v[5]; float sum = 0.f;
        #pragma unroll
        for (int nt=0; nt<5; ++nt){
          const int j = nt*16 + colj;
          float xv = 0.f;
          if (j < 64){
            const int o = m*128 + (((((j>>3)<<4)) ^ ((m&7)<<4)) + (j&7)*2);
            const float resd = h2f(*(const unsigned short*)&sAh[o])
                             + h2f(*(const unsigned short*)&sAl[o]) * INV2048;
            xv = __fadd_rn(resd, __fadd_rn(acc3[nt][rb][r], b2v[nt]));
          } else if (j < 66){
            xv = __fadd_rn(enew[rb][r][j-64], __fadd_rn(acc3[nt][rb][r], b2v[nt]));
          }
          v[nt] = xv;
          sum += xv;
        }
        #pragma unroll
        for (int mm=1; mm<16; mm<<=1) sum += __shfl_xor(sum, mm, 64);
        const float mean = sum / 66.0f;
        float d[5]; float sq = 0.f;
        #pragma unroll
        for (int nt=0; nt<5; ++nt){
          const int j = nt*16 + colj;
          d[nt] = (j < 66) ? __fsub_rn(v[nt], mean) : 0.f;
          sq = __fadd_rn(sq, __fmul_rn(d[nt], d[nt]));
        }
        #pragma unroll
        for (int mm=1; mm<16; mm<<=1) sq += __shfl_xor(sq, mm, 64);
        const float var  = sq / 66.0f;
        const float rstd = 1.0f / sqrtf(var + 1e-5f);
        if (medge){
          float* mrow = medge + (size_t)(ebase + m)*68;
          #pragma unroll
          for (int nt=0; nt<5; ++nt){
            const int j = nt*16 + colj;
            if (j < 66)
              mrow[j] = __fadd_rn(__fmul_rn(__fmul_rn(d[nt], rstd), lgv[nt]), lbv[nt]);
          }
        } else {
          float* arow = agg + (size_t)sCol[m]*66;
          #pragma unroll
          for (int nt=0; nt<5; ++nt){
            const int j = nt*16 + colj;
            if (j < 66)
              atomicAdd(arow + j, __fadd_rn(__fmul_rn(__fmul_rn(d[nt], rstd), lgv[nt]), lbv[nt]));
          }
        }
      }
    }
  }
}

// ---------------- node kernel: NodeModel.mlp_2 ----------------
__global__ __launch_bounds__(256,2)
void k_node(float* __restrict__ nodes,
            const float* __restrict__ agg, const float* __restrict__ invc,
            const unsigned short* __restrict__ wf,
            const float* __restrict__ b1, const float* __restrict__ resb,
            const float* __restrict__ b2, const float* __restrict__ lng,
            const float* __restrict__ lnb,
            const float* __restrict__ n2w1_tail,   // n2_w1 rows 128,129 (stride 128)
            const float* __restrict__ n2resw_tail) // n2_res_w rows 128,129 (stride 64)
{
  __shared__ __align__(16) unsigned char sAh[128*128];  // nodes f16 hi
  __shared__ __align__(16) unsigned char sAl[128*128];  // nodes f16 scaled-res
  __shared__ __align__(16) unsigned char sBH[128*256];  // agg hi/res; later H3 (256B rows)
  __shared__ float sAgg2[128][2];

  const int tid = threadIdx.x;
  const int nbase = blockIdx.x * 128;

  { // staging
    const int r = tid & 127, h = tid >> 7;
    const int node = nbase + r;
    const int swz = (r & 7) << 4;
    if (h == 0){
      const float4* sp = (const float4*)(nodes + (size_t)node*64);
      #pragma unroll
      for (int c = 0; c < 8; ++c){
        const float4 f0 = sp[2*c], f1 = sp[2*c+1];
        float v[8] = {f0.x,f0.y,f0.z,f0.w,f1.x,f1.y,f1.z,f1.w};
        s16x8 hh, rr; split8v(v, hh, rr);
        const int o = r*128 + ((c*16) ^ swz);
        *(s16x8*)&sAh[o] = hh;
        *(s16x8*)&sAl[o] = rr;
      }
    } else {
      const float iv = invc ? invc[node] : 1.0f;
      const float* ar = agg + (size_t)node*66;
      #pragma unroll
      for (int c = 0; c < 8; ++c){
        float v[8];
        #pragma unroll
        for (int i=0;i<8;++i) v[i] = invc ? ar[c*8+i]*iv : ar[c*8+i];
        s16x8 hh, rr; split8v(v, hh, rr);
        const int o = r*128 + ((c*16) ^ swz);
        *(s16x8*)&sBH[o] = hh;
        *(s16x8*)&sBH[16384 + o] = rr;
      }
      sAgg2[r][0] = invc ? ar[64]*iv : ar[64];
      sAgg2[r][1] = invc ? ar[65]*iv : ar[65];
    }
  }
  __syncthreads();

  const int lane  = tid & 63;
  const int wv    = tid >> 6;
  const int colj  = lane & 15;
  const int g     = lane >> 4;
  const int rowA0 = wv*32 + colj;
  const int mrow0 = wv*32 + g*4;

  float a0r[2][4], a1r[2][4];
  #pragma unroll
  for (int rb=0; rb<2; ++rb)
    #pragma unroll
    for (int r=0; r<4; ++r){
      const int m = mrow0 + rb*16 + r;
      a0r[rb][r] = sAgg2[m][0]; a1r[rb][r] = sAgg2[m][1];
    }

  // ---- GEMM1: [128,128] @ W1ext -> [128,192] in two nt-halves (VGPR) ----
  f32x4 acc1[12][2];
  #pragma unroll
  for (int i=0;i<12;++i){ acc1[i][0] = f32x4{0,0,0,0}; acc1[i][1] = f32x4{0,0,0,0}; }
  #pragma unroll
  for (int half = 0; half < 2; ++half){
    f32x4 aR[6][2];
    #pragma unroll
    for (int i=0;i<6;++i){ aR[i][0] = f32x4{0,0,0,0}; aR[i][1] = f32x4{0,0,0,0}; }
    #pragma unroll
    for (int ks = 0; ks < 4; ++ks){
      const int ch = (ks&1)*4 + g;
      const unsigned char* pH = (ks<2) ? sAh : sBH;
      const unsigned char* pL = (ks<2) ? sAl : (sBH + 16384);
      const int r1 = rowA0 + 16;
      const int o0 = rowA0*128 + ((ch*16) ^ ((rowA0&7)<<4));
      const int o1 = r1*128    + ((ch*16) ^ ((r1&7)<<4));
      const f16x8 ah0 = *(const f16x8*)&pH[o0];
      const f16x8 ah1 = *(const f16x8*)&pH[o1];
      const f16x8 ar0 = *(const f16x8*)&pL[o0];
      const f16x8 ar1 = *(const f16x8*)&pL[o1];
      const f16x8* bh = (const f16x8*)(wf + WOFF_T3) + (ks*12 + half*6)*64 + lane;
      const f16x8* bl = (const f16x8*)(wf + WOFF_T3 + WLO) + (ks*12 + half*6)*64 + lane;
      #pragma unroll
      for (int t = 0; t < 6; ++t){
        const int nt = half*6 + t;
        const f16x8 b1 = bh[t*64];
        const f16x8 b2 = bl[t*64];
        acc1[nt][0] = MFMAH(ah0, b1, acc1[nt][0]);
        aR[t][0]    = MFMAH(ar0, b1, aR[t][0]);
        aR[t][0]    = MFMAH(ah0, b2, aR[t][0]);
        acc1[nt][1] = MFMAH(ah1, b1, acc1[nt][1]);
        aR[t][1]    = MFMAH(ar1, b1, aR[t][1]);
        aR[t][1]    = MFMAH(ah1, b2, aR[t][1]);
      }
    }
    #pragma unroll
    for (int t=0;t<6;++t)
      #pragma unroll
      for (int rb=0; rb<2; ++rb)
        #pragma unroll
        for (int r=0; r<4; ++r)
          acc1[half*6+t][rb][r] += aR[t][rb][r] * INV2048;
  }
  { // agg cols 64,65 (W rows 128,129) exact fp32
    #pragma unroll
    for (int nt=0; nt<12; ++nt){
      const int j = nt*16 + colj;
      float w0, w1;
      if (j < 128){ w0 = n2w1_tail[j]; w1 = n2w1_tail[128 + j]; }
      else { w0 = n2resw_tail[j-128]; w1 = n2resw_tail[64 + (j-128)]; }
      #pragma unroll
      for (int rb=0; rb<2; ++rb)
        #pragma unroll
        for (int r=0; r<4; ++r)
          acc1[nt][rb][r] += a0r[rb][r]*w0 + a1r[rb][r]*w1;
    }
  }
  { // fold bias+relu into acc1 hidden part
    #pragma unroll
    for (int nt=0; nt<8; ++nt){
      const float bb = b1[nt*16 + colj];
      #pragma unroll
      for (int rb=0; rb<2; ++rb)
        #pragma unroll
        for (int r=0; r<4; ++r)
          acc1[nt][rb][r] = fmaxf(acc1[nt][rb][r] + bb, 0.f);
    }
  }

  __syncthreads();   // all reads of sBH done before overwrite with H3

  { // H3 hi (f16) -> LDS (256B rows)
    #pragma unroll
    for (int nt=0; nt<8; ++nt){
      const int j = nt*16 + colj;
      const int co = (j>>3)<<4, wi = (j&7)*2;
      #pragma unroll
      for (int rb=0; rb<2; ++rb)
        #pragma unroll
        for (int r=0; r<4; ++r){
          const int m = mrow0 + rb*16 + r;
          unsigned short us, ur; split16(acc1[nt][rb][r], us, ur);
          *(unsigned short*)&sBH[m*256 + ((co ^ ((m&7)<<4)) + wi)] = us;
        }
    }
  }
  __syncthreads();

  // ---- GEMM2-hi: acc2 += H3hi@W1 ; acc2R += H3hi@W2 ----
  f32x4 acc2[4][2], acc2R[4][2];
  #pragma unroll
  for (int i=0;i<4;++i){
    acc2[i][0] = f32x4{0,0,0,0}; acc2[i][1] = f32x4{0,0,0,0};
    acc2R[i][0] = f32x4{0,0,0,0}; acc2R[i][1] = f32x4{0,0,0,0};
  }
  #pragma unroll
  for (int ks=0; ks<4; ++ks){
    const int ch = ks*4 + g;
    const int r1 = rowA0 + 16;
    const f16x8 a0 = *(const f16x8*)&sBH[rowA0*256 + ((ch*16) ^ ((rowA0&7)<<4))];
    const f16x8 a1 = *(const f16x8*)&sBH[r1*256    + ((ch*16) ^ ((r1&7)<<4))];
    const f16x8* bh = (const f16x8*)(wf + WOFF_T4) + (ks*4)*64 + lane;
    const f16x8* bl = (const f16x8*)(wf + WOFF_T4 + WLO) + (ks*4)*64 + lane;
    #pragma unroll
    for (int nt = 0; nt < 4; ++nt){
      const f16x8 b1 = bh[nt*64];
      const f16x8 b2 = bl[nt*64];
      acc2[nt][0]  = MFMAH(a0, b1, acc2[nt][0]);
      acc2R[nt][0] = MFMAH(a0, b2, acc2R[nt][0]);
      acc2[nt][1]  = MFMAH(a1, b1, acc2[nt][1]);
      acc2R[nt][1] = MFMAH(a1, b2, acc2R[nt][1]);
    }
  }
  __syncthreads();

  { // H3 scaled-residual -> LDS
    #pragma unroll
    for (int nt=0; nt<8; ++nt){
      const int j = nt*16 + colj;
      const int co = (j>>3)<<4, wi = (j&7)*2;
      #pragma unroll
      for (int rb=0; rb<2; ++rb)
        #pragma unroll
        for (int r=0; r<4; ++r){
          const int m = mrow0 + rb*16 + r;
          unsigned short us, ur; split16(acc1[nt][rb][r], us, ur);
          *(unsigned short*)&sBH[m*256 + ((co ^ ((m&7)<<4)) + wi)] = ur;
        }
    }
  }
  __syncthreads();

  // ---- GEMM2-lo: acc2R += H3res@W1 ; fold ----
  #pragma unroll
  for (int ks=0; ks<4; ++ks){
    const int ch = ks*4 + g;
    const int r1 = rowA0 + 16;
    const f16x8 a0 = *(const f16x8*)&sBH[rowA0*256 + ((ch*16) ^ ((rowA0&7)<<4))];
    const f16x8 a1 = *(const f16x8*)&sBH[r1*256    + ((ch*16) ^ ((r1&7)<<4))];
    const f16x8* bh = (const f16x8*)(wf + WOFF_T4) + (ks*4)*64 + lane;
    #pragma unroll
    for (int nt = 0; nt < 4; ++nt){
      const f16x8 b1 = bh[nt*64];
      acc2R[nt][0] = MFMAH(a0, b1, acc2R[nt][0]);
      acc2R[nt][1] = MFMAH(a1, b1, acc2R[nt][1]);
    }
  }
  #pragma unroll
  for (int nt=0; nt<4; ++nt)
    #pragma unroll
    for (int rb=0; rb<2; ++rb)
      #pragma unroll
      for (int r=0; r<4; ++r)
        acc2[nt][rb][r] += acc2R[nt][rb][r] * INV2048;

  // ---- epilogue: LN(64) two-pass (np-matching) + residual + "+nodes" ----
  {
    float b2v[4], rbv[4], lgv[4], lbv[4];
    #pragma unroll
    for (int nt=0; nt<4; ++nt){
      const int j = nt*16 + colj;
      b2v[nt] = b2[j]; rbv[nt] = resb[j]; lgv[nt] = lng[j]; lbv[nt] = lnb[j];
    }
    #pragma unroll
    for (int rb=0; rb<2; ++rb){
      #pragma unroll
      for (int r=0; r<4; ++r){
        const int m = mrow0 + rb*16 + r;
        const int node = nbase + m;
        float v[4]; float sum = 0.f;
        #pragma unroll
        for (int nt=0; nt<4; ++nt){
          const float resi = __fadd_rn(acc1[8+nt][rb][r], rbv[nt]);
          const float hh   = __fadd_rn(acc2[nt][rb][r], b2v[nt]);
          const float xv = __fadd_rn(resi, hh);
          v[nt] = xv; sum += xv;
        }
        #pragma unroll
        for (int mm=1; mm<16; mm<<=1) sum += __shfl_xor(sum, mm, 64);
        const float mean = sum / 64.0f;
        float d[4]; float sq = 0.f;
        #pragma unroll
        for (int nt=0; nt<4; ++nt){
          d[nt] = __fsub_rn(v[nt], mean);
          sq = __fadd_rn(sq, __fmul_rn(d[nt], d[nt]));
        }
        #pragma unroll
        for (int mm=1; mm<16; mm<<=1) sq += __shfl_xor(sq, mm, 64);
        const float var  = sq / 64.0f;
        const float rstd = 1.0f / sqrtf(var + 1e-5f);
        #pragma unroll
        for (int nt=0; nt<4; ++nt){
          const int j = nt*16 + colj;
          const size_t idx = (size_t)node*64 + j;
          const float lnout = __fadd_rn(__fmul_rn(__fmul_rn(d[nt], rstd), lgv[nt]), lbv[nt]);
          nodes[idx] = __fadd_rn(lnout, nodes[idx]);
        }
      }
    }
  }
}

__global__ void k_copy(const float* __restrict__ nodes, float* __restrict__ out){
  const int i = blockIdx.x*256 + threadIdx.x;   // grid exactly NACT*16
  if (i < NACT*16)
    ((float4*)out)[i] = ((const float4*)nodes)[NPAD*16 + i];
}

extern "C" void kernel_launch(void* const* d_in, const int* in_sizes, int n_in,
                              void* d_out, int out_size, void* d_ws, size_t ws_size,
                              hipStream_t stream){
  const float* x       = (const float*)d_in[0];
  const int*   ei      = (const int*)  d_in[1];
  const float* eattr   = (const float*)d_in[2];
  const float* e_res_w = (const float*)d_in[3];
  const float* e_res_b = (const float*)d_in[4];
  const float* e_w1    = (const float*)d_in[5];
  const float* e_b1    = (const float*)d_in[6];
  const float* e_w2    = (const float*)d_in[7];
  const float* e_b2    = (const float*)d_in[8];
  const float* e_ln_g  = (const float*)d_in[9];
  const float* e_ln_b  = (const float*)d_in[10];
  const float* n1_w1   = (const float*)d_in[11];
  const float* n1_b1   = (const float*)d_in[12];
  const float* n1_w2   = (const float*)d_in[13];
  const float* n1_b2   = (const float*)d_in[14];
  const float* n1_ln_g = (const float*)d_in[15];
  const float* n1_ln_b = (const float*)d_in[16];
  const float* n2_res_w= (const float*)d_in[17];
  const float* n2_res_b= (const float*)d_in[18];
  const float* n2_w1   = (const float*)d_in[19];
  const float* n2_b1   = (const float*)d_in[20];
  const float* n2_w2   = (const float*)d_in[21];
  const float* n2_b2   = (const float*)d_in[22];
  const float* n2_ln_g = (const float*)d_in[23];
  const float* n2_ln_b = (const float*)d_in[24];

  if (ws_size < 21364736u) return;

  char* ws = (char*)d_ws;
  float*          nodes = (float*)(ws + 0);             // NN*64 f32
  float*          edges = (float*)(ws + 8388608);       // NEDGE*2 f32
  float*          agg   = (float*)(ws + 10223616);      // NN*66 f32
  int*            cnt   = (int*)(ws + 18874368);
  float*          invc  = (float*)(ws + 19005440);
  unsigned short* wfrag = (unsigned short*)(ws + 19136512);  // ends 21364736
  // fast-path extras
  int*   row_start = (int*)(ws + 21364736);             // NN+1 ints
  int*   fill      = (int*)(ws + 21495936);
  int*   ssrc      = (int*)(ws + 21627008);
  int*   sdst      = (int*)(ws + 22544512);
  int*   seid      = (int*)(ws + 23462016);
  float* medge     = (float*)(ws + 24379520);           // NEDGE*68 f32, ends 86769792

  const bool fast = ws_size >= 86769792u;

  k_pack<<<dim3(12,8,5),256,0,stream>>>(e_w1, e_res_w, n1_w1, n1_w2, n2_w1, n2_res_w, n2_w2, wfrag);
  k_init<<<8192,256,0,stream>>>(x, eattr, nodes, edges, cnt);
  k_count<<<896,256,0,stream>>>(ei, cnt);
  k_inv<<<128,256,0,stream>>>(cnt, invc, fast ? fill : cnt /*dummy*/);

  const int* sidx = ei;
  const int* didx = ei + NEDGE;
  const int* eidx = nullptr;
  if (fast){
    k_scan<<<1,256,0,stream>>>(cnt, row_start);
    k_place<<<896,256,0,stream>>>(ei, row_start, fill, ssrc, sdst, seid);
    k_sortb<<<128,256,0,stream>>>(row_start, seid, ssrc);
    sidx = ssrc; didx = sdst; eidx = seid;
  }

  for (int l = 0; l < NLAY; ++l){
    if (!fast) k_zero_agg<<<8448,256,0,stream>>>(agg);
    k_edge<<<1792,256,0,stream>>>(sidx, didx, eidx, edges, nodes,
        wfrag + (size_t)l*WLAYER, agg, fast ? medge : nullptr,
        e_b1 + l*128, e_w2 + l*256, e_b2 + l*2, e_res_b + l*2, e_ln_g + l*2, e_ln_b + l*2,
        e_w1 + ((size_t)l*130 + 128)*128,
        e_res_w + ((size_t)l*130 + 128)*2,
        n1_w1 + ((size_t)l*66 + 64)*128,
        n1_b1 + l*128, n1_b2 + l*66, n1_ln_g + l*66, n1_ln_b + l*66);
    if (fast) k_agg<<<8192,256,0,stream>>>(medge, row_start, cnt, agg);
    k_node<<<256,256,0,stream>>>(nodes, agg, fast ? nullptr : invc,
        wfrag + (size_t)l*WLAYER,
        n2_b1 + l*128, n2_res_b + l*64, n2_b2 + l*64, n2_ln_g + l*64, n2_ln_b + l*64,
        n2_w1 + ((size_t)l*130 + 128)*128,
        n2_res_w + ((size_t)l*130 + 128)*64);
  }
  k_copy<<<1792,256,0,stream>>>(nodes, (float*)d_out);
}

// Round 7
// 2478.114 us; speedup vs baseline: 1.1063x; 1.1063x over previous
//
#include <hip/hip_runtime.h>

#define NN    32768
#define NACT  28672
#define NPAD  4096
#define NEDGE 229376
#define NLAY  8

// packed weight layout: per layer, W1 plane (f16) then W2 plane (f16, (w-w1)*2048)
#define WOFF_T0 0        // edge W1ext : KT=4 NT=9
#define WOFF_T1 18432    // mlp1 W1    : KT=2 NT=8
#define WOFF_T2 26624    // mlp1 W2ext : KT=4 NT=5
#define WOFF_T3 36864    // node W1ext : KT=4 NT=12
#define WOFF_T4 61440    // node W2    : KT=4 NT=4
#define WLO     69632
#define WLAYER  139264

typedef __attribute__((ext_vector_type(8))) short s16x8;
typedef __attribute__((ext_vector_type(8))) _Float16 f16x8;
typedef __attribute__((ext_vector_type(4))) float f32x4;

#define MFMAH(a,b,c) __builtin_amdgcn_mfma_f32_16x16x32_f16((a),(b),(c),0,0,0)
#define INV2048 4.8828125e-4f

__device__ __forceinline__ unsigned short f2h(float f){
  union { _Float16 h; unsigned short u; } v; v.h = (_Float16)f; return v.u;
}
__device__ __forceinline__ float h2f(unsigned short u){
  union { unsigned short u; _Float16 h; } v; v.u = u; return (float)v.h;
}
// scaled f16 split: a = h + r/2048, |err| ~ 2^-24|a|; denormal-guarded
__device__ __forceinline__ void split16(float a, unsigned short& h, unsigned short& r){
  float hf = 0.f; unsigned short hu = 0;
  if (__builtin_fabsf(a) >= 6.1035156e-5f){ hu = f2h(a); hf = h2f(hu); }
  h = hu;
  r = f2h((a - hf) * 2048.0f);
}
__device__ __forceinline__ void split8v(const float* v, s16x8& h, s16x8& r){
  #pragma unroll
  for (int i=0;i<8;++i){
    unsigned short hh, rr; split16(v[i], hh, rr);
    h[i] = (short)hh; r[i] = (short)rr;
  }
}

// ---------------- weight packing (f16 W1 + scaled-f16 W2 planes) ----------------
__global__ void k_pack(const float* __restrict__ ew1, const float* __restrict__ eresw,
                       const float* __restrict__ n1w1, const float* __restrict__ n1w2,
                       const float* __restrict__ n2w1, const float* __restrict__ n2resw,
                       const float* __restrict__ n2w2,
                       unsigned short* __restrict__ wfrag){
  const int l = blockIdx.y, T = blockIdx.z;
  int KT, NT, off;
  if (T==0){ KT=4; NT=9;  off=WOFF_T0; }
  else if (T==1){ KT=2; NT=8;  off=WOFF_T1; }
  else if (T==2){ KT=4; NT=5;  off=WOFF_T2; }
  else if (T==3){ KT=4; NT=12; off=WOFF_T3; }
  else          { KT=4; NT=4;  off=WOFF_T4; }
  const int f = blockIdx.x*256 + threadIdx.x;
  if (f >= KT*NT*64) return;
  const int lane = f & 63;
  const int fn = f >> 6;
  const int nt = fn % NT, ks = fn / NT;
  const int n  = nt*16 + (lane & 15);
  const int kb = ks*32 + (lane >> 4)*8;
  s16x8 vh, vl;
  #pragma unroll
  for (int i=0;i<8;++i){
    const int k = kb + i;
    float w = 0.f;
    if (T==0){
      if (n < 128)      w = ew1[((size_t)l*130 + k)*128 + n];
      else if (n < 130) w = eresw[((size_t)l*130 + k)*2 + (n-128)];
    } else if (T==1){
      w = n1w1[((size_t)l*66 + k)*128 + n];
    } else if (T==2){
      if (n < 66) w = n1w2[((size_t)l*128 + k)*66 + n];
    } else if (T==3){
      if (n < 128) w = n2w1[((size_t)l*130 + k)*128 + n];
      else         w = n2resw[((size_t)l*130 + k)*64 + (n-128)];
    } else {
      w = n2w2[((size_t)l*128 + k)*64 + n];
    }
    unsigned short hh, rr; split16(w, hh, rr);
    vh[i] = (short)hh; vl[i] = (short)rr;
  }
  *(s16x8*)(wfrag + (size_t)l*WLAYER + off + (size_t)f*8) = vh;
  *(s16x8*)(wfrag + (size_t)l*WLAYER + off + WLO + (size_t)f*8) = vl;
}

// ---------------- init / degree / sort ----------------
__global__ void k_init(const float* __restrict__ x, const float* __restrict__ ea,
                       float* __restrict__ nodes, float* __restrict__ edges,
                       int* __restrict__ cnt){
  const int i = blockIdx.x*256 + threadIdx.x;   // grid = exactly NN*64
  nodes[i] = (i >= NPAD*64) ? x[i - NPAD*64] : 0.f;
  if (i < NEDGE*2) edges[i] = ea[i];
  if (i < NN) cnt[i] = 0;
}

__global__ void k_count(const int* __restrict__ ei, int* __restrict__ cnt){
  const int e = blockIdx.x*256 + threadIdx.x;
  if (e < NEDGE) atomicAdd(&cnt[ei[NEDGE + e]], 1);
}

__global__ void k_inv(const int* __restrict__ cnt, float* __restrict__ invc,
                      int* __restrict__ fill){
  const int n = blockIdx.x*256 + threadIdx.x;
  if (n < NN){ invc[n] = 1.0f / (float)max(cnt[n], 1); fill[n] = 0; }
}

__global__ void k_scan(const int* __restrict__ cnt, int* __restrict__ row_start){
  __shared__ int part[256];
  const int t = threadIdx.x;
  int s = 0;
  for (int i=0;i<128;++i) s += cnt[t*128+i];
  part[t] = s;
  __syncthreads();
  if (t == 0){
    int run = 0;
    for (int i=0;i<256;++i){ const int v = part[i]; part[i] = run; run += v; }
  }
  __syncthreads();
  int base = part[t];
  for (int i=0;i<128;++i){ row_start[t*128+i] = base; base += cnt[t*128+i]; }
  if (t == 255) row_start[NN] = base;
}

__global__ void k_place(const int* __restrict__ ei, const int* __restrict__ row_start,
                        int* __restrict__ fill, int* __restrict__ ssrc,
                        int* __restrict__ sdst, int* __restrict__ seid){
  const int e = blockIdx.x*256 + threadIdx.x;
  if (e >= NEDGE) return;
  const int d = ei[NEDGE + e];
  const int pos = row_start[d] + atomicAdd(&fill[d], 1);
  ssrc[pos] = ei[e];
  sdst[pos] = d;
  seid[pos] = e;
}

// deterministic within-bucket order: insertion sort by eid (deg ~7)
__global__ void k_sortb(const int* __restrict__ row_start,
                        int* __restrict__ seid, int* __restrict__ ssrc){
  const int n = blockIdx.x*256 + threadIdx.x;
  if (n >= NN) return;
  const int rs = row_start[n], re = row_start[n+1];
  for (int i = rs+1; i < re; ++i){
    const int e = seid[i], s = ssrc[i];
    int j = i-1;
    while (j >= rs && seid[j] > e){ seid[j+1]=seid[j]; ssrc[j+1]=ssrc[j]; --j; }
    seid[j+1] = e; ssrc[j+1] = s;
  }
}

// permute edge_attr into sorted order (edges stays sorted all layers)
__global__ void k_perm(const float* __restrict__ ea, const int* __restrict__ seid,
                       float* __restrict__ edges){
  const int e = blockIdx.x*256 + threadIdx.x;
  if (e < NEDGE){
    const int o = seid[e];
    ((float2*)edges)[e] = ((const float2*)ea)[o];
  }
}

__global__ void k_zero_agg(float* __restrict__ agg64, float* __restrict__ agg2){
  const int i = blockIdx.x*256 + threadIdx.x;   // grid exactly NN*64
  agg64[i] = 0.f;
  if (i < NN*2) agg2[i] = 0.f;
}

// CSR aggregation: one wave per node, no atomics; eid-ascending order matches
// np.add.at; true fp32 division matches the reference's "/ cnt".
__global__ __launch_bounds__(256)
void k_agg(const float* __restrict__ medge64, const float* __restrict__ medge2,
           const int* __restrict__ row_start, const int* __restrict__ cnt,
           float* __restrict__ agg64, float* __restrict__ agg2){
  const int n = blockIdx.x*4 + (threadIdx.x >> 6);
  const int lane = threadIdx.x & 63;
  const int rs = row_start[n], re = row_start[n+1];
  const float cf = (float)max(cnt[n], 1);
  float a = 0.f, b = 0.f;
  for (int r = rs; r < re; ++r){
    a = __fadd_rn(a, medge64[(size_t)r*64 + lane]);
    if (lane < 2) b = __fadd_rn(b, medge2[(size_t)r*2 + lane]);
  }
  agg64[(size_t)n*64 + lane] = a / cf;
  if (lane < 2) agg2[(size_t)n*2 + lane] = b / cf;
}

// ---------------- fused edge kernel (64 edges/block): EdgeModel + mlp_1 ----------------
__global__ __launch_bounds__(256,4)
void k_edge(const int* __restrict__ sidx, const int* __restrict__ didx,
            float* __restrict__ edges,
            const float* __restrict__ nodes,
            const unsigned short* __restrict__ wf,
            float* __restrict__ agg64, float* __restrict__ agg2,
            float* __restrict__ medge64, float* __restrict__ medge2,
            const float* __restrict__ eb1, const float* __restrict__ ew2,
            const float* __restrict__ eb2, const float* __restrict__ eresb,
            const float* __restrict__ elng, const float* __restrict__ elnb,
            const float* __restrict__ ew1_tail,   // e_w1 rows 128,129 (stride 128)
            const float* __restrict__ eresw_tail, // e_res_w rows 128,129 (stride 2)
            const float* __restrict__ n1w1_tail,  // n1_w1 rows 64,65 (stride 128)
            const float* __restrict__ n1b1, const float* __restrict__ n1b2,
            const float* __restrict__ n1lng, const float* __restrict__ n1lnb)
{
  __shared__ __align__(16) unsigned char sAh[64*128];  // src f16 hi
  __shared__ __align__(16) unsigned char sAl[64*128];  // src f16 scaled-res
  __shared__ __align__(16) unsigned char sBH[64*256];  // dst hi[0:8K) res[8K:16K); later H2 (256B rows)
  __shared__ float sEold[64][2];
  __shared__ int   sCol[64];

  const int tid = threadIdx.x;
  const int ebase = blockIdx.x * 64;

  { // staging: 2 threads per row; tid<128 src, tid>=128 dst
    const int r = (tid & 127) >> 1;
    const int half = tid & 1;
    const int es = ebase + r;
    const int swz = (r & 7) << 4;
    if (tid < 128){
      const int sn = sidx[es];
      const float4* sp = (const float4*)(nodes + (size_t)sn*64);
      #pragma unroll
      for (int cc = 0; cc < 4; ++cc){
        const int c = half*4 + cc;
        const float4 f0 = sp[2*c], f1 = sp[2*c+1];
        float v[8] = {f0.x,f0.y,f0.z,f0.w,f1.x,f1.y,f1.z,f1.w};
        s16x8 hh, rr; split8v(v, hh, rr);
        const int o = r*128 + ((c*16) ^ swz);
        *(s16x8*)&sAh[o] = hh;
        *(s16x8*)&sAl[o] = rr;
      }
    } else {
      const int dn = didx[es];
      const float4* dp = (const float4*)(nodes + (size_t)dn*64);
      #pragma unroll
      for (int cc = 0; cc < 4; ++cc){
        const int c = half*4 + cc;
        const float4 f0 = dp[2*c], f1 = dp[2*c+1];
        float v[8] = {f0.x,f0.y,f0.z,f0.w,f1.x,f1.y,f1.z,f1.w};
        s16x8 hh, rr; split8v(v, hh, rr);
        const int o = r*128 + ((c*16) ^ swz);
        *(s16x8*)&sBH[o] = hh;
        *(s16x8*)&sBH[8192 + o] = rr;
      }
      if (half == 0){
        const float2 ev = *(const float2*)(edges + (size_t)es*2);
        sEold[r][0] = ev.x; sEold[r][1] = ev.y;
        sCol[r] = dn;
      }
    }
  }
  __syncthreads();

  const int lane  = tid & 63;
  const int wv    = tid >> 6;
  const int colj  = lane & 15;
  const int g     = lane >> 4;
  const int rowA0 = wv*16 + colj;      // A-frag row
  const int mrow0 = wv*16 + g*4;       // C/D row base (add r)

  float e0r[4], e1r[4];
  #pragma unroll
  for (int r=0; r<4; ++r){
    const int m = mrow0 + r;
    e0r[r] = sEold[m][0]; e1r[r] = sEold[m][1];
  }

  // ---- phase 1: Hext[64,144] = X[64,128] @ W1ext + e-cols fp32 rank-2 ----
  f32x4 acc1[9], accR[9];
  #pragma unroll
  for (int i=0;i<9;++i){ acc1[i] = f32x4{0,0,0,0}; accR[i] = f32x4{0,0,0,0}; }
  {
    #pragma unroll
    for (int ks = 0; ks < 4; ++ks){
      const int ch = (ks&1)*4 + g;
      const unsigned char* pH = (ks<2) ? sAh : sBH;
      const unsigned char* pL = (ks<2) ? sAl : (sBH + 8192);
      const int o0 = rowA0*128 + ((ch*16) ^ ((rowA0&7)<<4));
      const f16x8 ah = *(const f16x8*)&pH[o0];
      const f16x8 ar = *(const f16x8*)&pL[o0];
      const f16x8* bh = (const f16x8*)(wf + WOFF_T0) + (ks*9)*64 + lane;
      const f16x8* bl = (const f16x8*)(wf + WOFF_T0 + WLO) + (ks*9)*64 + lane;
      #pragma unroll
      for (int nt = 0; nt < 9; ++nt){
        const f16x8 b1 = bh[nt*64];
        const f16x8 b2 = bl[nt*64];
        acc1[nt] = MFMAH(ah, b1, acc1[nt]);
        accR[nt] = MFMAH(ar, b1, accR[nt]);
        accR[nt] = MFMAH(ah, b2, accR[nt]);
      }
    }
    #pragma unroll
    for (int nt=0; nt<9; ++nt)
      #pragma unroll
      for (int r=0; r<4; ++r)
        acc1[nt][r] += accR[nt][r] * INV2048;
    #pragma unroll
    for (int nt=0; nt<9; ++nt){
      const int j = nt*16 + colj;
      float w0, w1;
      if (nt < 8){ w0 = ew1_tail[j]; w1 = ew1_tail[128 + j]; }
      else { w0 = (colj<2) ? eresw_tail[colj] : 0.f; w1 = (colj<2) ? eresw_tail[2+colj] : 0.f; }
      #pragma unroll
      for (int r=0; r<4; ++r)
        acc1[nt][r] += e0r[r]*w0 + e1r[r]*w1;
    }
  }

  // ---- phase 2: edge head (N=2) + LN(2) + residual ----
  float enew[4][2];
  {
    float2 w2v[8]; float b1v[8];
    #pragma unroll
    for (int nt=0; nt<8; ++nt){
      const int j = nt*16 + colj;
      w2v[nt] = *(const float2*)(ew2 + (size_t)j*2);
      b1v[nt] = eb1[j];
    }
    const float rb0 = eresb[0], rb1 = eresb[1];
    const float g0 = elng[0], g1 = elng[1], lb0 = elnb[0], lb1 = elnb[1];
    const float bb0 = eb2[0], bb1 = eb2[1];
    #pragma unroll
    for (int r=0; r<4; ++r){
      float v0 = 0.f, v1 = 0.f;
      #pragma unroll
      for (int nt=0; nt<8; ++nt){
        const float h = fmaxf(acc1[nt][r] + b1v[nt], 0.f);
        v0 = fmaf(h, w2v[nt].x, v0);
        v1 = fmaf(h, w2v[nt].y, v1);
      }
      const float resv = acc1[8][r];
      if (colj == 0) v0 += resv + rb0;
      if (colj == 1) v1 += resv + rb1;
      #pragma unroll
      for (int mm=1; mm<16; mm<<=1){
        v0 += __shfl_xor(v0, mm, 64);
        v1 += __shfl_xor(v1, mm, 64);
      }
      v0 += bb0; v1 += bb1;
      // LayerNorm(2) with np-matching rounding
      const float m2 = __fmul_rn(__fadd_rn(v0, v1), 0.5f);
      const float d0 = __fsub_rn(v0, m2);
      const float d1 = __fsub_rn(v1, m2);
      const float var = __fmul_rn(__fadd_rn(__fmul_rn(d0,d0), __fmul_rn(d1,d1)), 0.5f);
      const float rstd = 1.0f / sqrtf(var + 1e-5f);
      const int m = mrow0 + r;
      const float e0 = __fadd_rn(__fadd_rn(__fmul_rn(__fmul_rn(d0, rstd), g0), lb0), e0r[r]);
      const float e1 = __fadd_rn(__fadd_rn(__fmul_rn(__fmul_rn(d1, rstd), g1), lb1), e1r[r]);
      enew[r][0] = e0; enew[r][1] = e1;
      if (colj == 0)
        *(float2*)(edges + (size_t)(ebase + m)*2) = make_float2(e0, e1);
    }
  }

  // ---- phase 3: H2[64,128] = src[64,64] @ n1_w1 (+ fp32 rank-2 for e) ----
  f32x4 acc2[8];
  {
    f32x4 acc2R[8];
    #pragma unroll
    for (int i=0;i<8;++i){ acc2[i] = f32x4{0,0,0,0}; acc2R[i] = f32x4{0,0,0,0}; }
    #pragma unroll
    for (int ks=0; ks<2; ++ks){
      const int ch = ks*4 + g;
      const int o0 = rowA0*128 + ((ch*16) ^ ((rowA0&7)<<4));
      const f16x8 ah = *(const f16x8*)&sAh[o0];
      const f16x8 ar = *(const f16x8*)&sAl[o0];
      const f16x8* bh = (const f16x8*)(wf + WOFF_T1) + (ks*8)*64 + lane;
      const f16x8* bl = (const f16x8*)(wf + WOFF_T1 + WLO) + (ks*8)*64 + lane;
      #pragma unroll
      for (int nt = 0; nt < 8; ++nt){
        const f16x8 b1 = bh[nt*64];
        const f16x8 b2 = bl[nt*64];
        acc2[nt]  = MFMAH(ah, b1, acc2[nt]);
        acc2R[nt] = MFMAH(ar, b1, acc2R[nt]);
        acc2R[nt] = MFMAH(ah, b2, acc2R[nt]);
      }
    }
    #pragma unroll
    for (int nt=0; nt<8; ++nt)
      #pragma unroll
      for (int r=0; r<4; ++r)
        acc2[nt][r] += acc2R[nt][r] * INV2048;
  }
  {
    #pragma unroll
    for (int nt=0; nt<8; ++nt){
      const int j = nt*16 + colj;
      const float w64 = n1w1_tail[j];
      const float w65 = n1w1_tail[128 + j];
      const float bb = n1b1[j];
      #pragma unroll
      for (int r=0; r<4; ++r){
        float h = acc2[nt][r] + enew[r][0]*w64 + enew[r][1]*w65 + bb;
        acc2[nt][r] = fmaxf(h, 0.f);
      }
    }
  }

  __syncthreads();   // all phase-1 reads of sBH done before overwrite

  // ---- phase 4a: H2 hi (f16) -> LDS (256B rows over sBH) ----
  {
    #pragma unroll
    for (int nt=0; nt<8; ++nt){
      const int j = nt*16 + colj;
      const int co = (j>>3)<<4, wi = (j&7)*2;
      #pragma unroll
      for (int r=0; r<4; ++r){
        const int m = mrow0 + r;
        unsigned short us, ur; split16(acc2[nt][r], us, ur);
        *(unsigned short*)&sBH[m*256 + ((co ^ ((m&7)<<4)) + wi)] = us;
      }
    }
  }
  __syncthreads();

  // ---- phase 4b-hi: acc3 += H2hi@W1 ; acc3R += H2hi@W2 ----
  f32x4 acc3[5], acc3R[5];
  #pragma unroll
  for (int i=0;i<5;++i){ acc3[i] = f32x4{0,0,0,0}; acc3R[i] = f32x4{0,0,0,0}; }
  #pragma unroll
  for (int ks=0; ks<4; ++ks){
    const int ch = ks*4 + g;
    const f16x8 a0 = *(const f16x8*)&sBH[rowA0*256 + ((ch*16) ^ ((rowA0&7)<<4))];
    const f16x8* bh = (const f16x8*)(wf + WOFF_T2) + (ks*5)*64 + lane;
    const f16x8* bl = (const f16x8*)(wf + WOFF_T2 + WLO) + (ks*5)*64 + lane;
    #pragma unroll
    for (int nt = 0; nt < 5; ++nt){
      const f16x8 b1 = bh[nt*64];
      const f16x8 b2 = bl[nt*64];
      acc3[nt]  = MFMAH(a0, b1, acc3[nt]);
      acc3R[nt] = MFMAH(a0, b2, acc3R[nt]);
    }
  }
  __syncthreads();

  // ---- phase 4a': H2 scaled-residual -> LDS ----
  {
    #pragma unroll
    for (int nt=0; nt<8; ++nt){
      const int j = nt*16 + colj;
      const int co = (j>>3)<<4, wi = (j&7)*2;
      #pragma unroll
      for (int r=0; r<4; ++r){
        const int m = mrow0 + r;
        unsigned short us, ur; split16(acc2[nt][r], us, ur);
        *(unsigned short*)&sBH[m*256 + ((co ^ ((m&7)<<4)) + wi)] = ur;
      }
    }
  }
  __syncthreads();

  // ---- phase 4b-lo: acc3R += H2res@W1 ; fold ----
  #pragma unroll
  for (int ks=0; ks<4; ++ks){
    const int ch = ks*4 + g;
    const f16x8 a0 = *(const f16x8*)&sBH[rowA0*256 + ((ch*16) ^ ((rowA0&7)<<4))];
    const f16x8* bh = (const f16x8*)(wf + WOFF_T2) + (ks*5)*64 + lane;
    #pragma unroll
    for (int nt = 0; nt < 5; ++nt){
      const f16x8 b1 = bh[nt*64];
      acc3R[nt] = MFMAH(a0, b1, acc3R[nt]);
    }
  }
  #pragma unroll
  for (int nt=0; nt<5; ++nt)
    #pragma unroll
    for (int r=0; r<4; ++r)
      acc3[nt][r] += acc3R[nt][r] * INV2048;

  // ---- phase 4c: LN(66) two-pass (np-matching) + emit ----
  {
    float b2v[5], lgv[5], lbv[5];
    #pragma unroll
    for (int nt=0; nt<5; ++nt){
      const int j = nt*16 + colj;
      const bool ok = j < 66;
      b2v[nt] = ok ? n1b2[j]  : 0.f;
      lgv[nt] = ok ? n1lng[j] : 0.f;
      lbv[nt] = ok ? n1lnb[j] : 0.f;
    }
    #pragma unroll
    for (int r=0; r<4; ++r){
      const int m = mrow0 + r;
      float v[5]; float sum = 0.f;
      #pragma unroll
      for (int nt=0; nt<5; ++nt){
        const int j = nt*16 + colj;
        float xv = 0.f;
        if (j < 64){
          const int o = m*128 + (((((j>>3)<<4)) ^ ((m&7)<<4)) + (j&7)*2);
          const float resd = h2f(*(const unsigned short*)&sAh[o])
                           + h2f(*(const unsigned short*)&sAl[o]) * INV2048;
          xv = __fadd_rn(resd, __fadd_rn(acc3[nt][r], b2v[nt]));
        } else if (j < 66){
          xv = __fadd_rn(enew[r][j-64], __fadd_rn(acc3[nt][r], b2v[nt]));
        }
        v[nt] = xv;
        sum += xv;
      }
      #pragma unroll
      for (int mm=1; mm<16; mm<<=1) sum += __shfl_xor(sum, mm, 64);
      const float mean = sum / 66.0f;
      float d[5]; float sq = 0.f;
      #pragma unroll
      for (int nt=0; nt<5; ++nt){
        const int j = nt*16 + colj;
        d[nt] = (j < 66) ? __fsub_rn(v[nt], mean) : 0.f;
        sq = __fadd_rn(sq, __fmul_rn(d[nt], d[nt]));
      }
      #pragma unroll
      for (int mm=1; mm<16; mm<<=1) sq += __shfl_xor(sq, mm, 64);
      const float var  = sq / 66.0f;
      const float rstd = 1.0f / sqrtf(var + 1e-5f);
      if (medge64){
        float* m64 = medge64 + (size_t)(ebase + m)*64;
        #pragma unroll
        for (int nt=0; nt<4; ++nt)
          m64[nt*16 + colj] = __fadd_rn(__fmul_rn(__fmul_rn(d[nt], rstd), lgv[nt]), lbv[nt]);
        if (colj < 2)
          medge2[(size_t)(ebase + m)*2 + colj] =
            __fadd_rn(__fmul_rn(__fmul_rn(d[4], rstd), lgv[4]), lbv[4]);
      } else {
        float* a64 = agg64 + (size_t)sCol[m]*64;
        #pragma unroll
        for (int nt=0; nt<4; ++nt)
          atomicAdd(a64 + nt*16 + colj, __fadd_rn(__fmul_rn(__fmul_rn(d[nt], rstd), lgv[nt]), lbv[nt]));
        if (colj < 2)
          atomicAdd(agg2 + (size_t)sCol[m]*2 + colj,
                    __fadd_rn(__fmul_rn(__fmul_rn(d[4], rstd), lgv[4]), lbv[4]));
      }
    }
  }
}

// ---------------- node kernel (64 nodes/block): NodeModel.mlp_2 ----------------
__global__ __launch_bounds__(256,4)
void k_node(float* __restrict__ nodes,
            const float* __restrict__ agg64, const float* __restrict__ agg2,
            const float* __restrict__ invc,
            const unsigned short* __restrict__ wf,
            const float* __restrict__ b1, const float* __restrict__ resb,
            const float* __restrict__ b2, const float* __restrict__ lng,
            const float* __restrict__ lnb,
            const float* __restrict__ n2w1_tail,   // n2_w1 rows 128,129 (stride 128)
            const float* __restrict__ n2resw_tail) // n2_res_w rows 128,129 (stride 64)
{
  __shared__ __align__(16) unsigned char sAh[64*128];  // nodes f16 hi
  __shared__ __align__(16) unsigned char sAl[64*128];  // nodes f16 scaled-res
  __shared__ __align__(16) unsigned char sBH[64*256];  // agg hi/res; later H3 (256B rows)
  __shared__ float sAgg2[64][2];

  const int tid = threadIdx.x;
  const int nbase = blockIdx.x * 64;

  { // staging: 2 threads per row
    const int r = (tid & 127) >> 1;
    const int half = tid & 1;
    const int node = nbase + r;
    const int swz = (r & 7) << 4;
    if (tid < 128){
      const float4* sp = (const float4*)(nodes + (size_t)node*64);
      #pragma unroll
      for (int cc = 0; cc < 4; ++cc){
        const int c = half*4 + cc;
        const float4 f0 = sp[2*c], f1 = sp[2*c+1];
        float v[8] = {f0.x,f0.y,f0.z,f0.w,f1.x,f1.y,f1.z,f1.w};
        s16x8 hh, rr; split8v(v, hh, rr);
        const int o = r*128 + ((c*16) ^ swz);
        *(s16x8*)&sAh[o] = hh;
        *(s16x8*)&sAl[o] = rr;
      }
    } else {
      const float iv = invc ? invc[node] : 1.0f;
      const float* a64 = agg64 + (size_t)node*64;
      #pragma unroll
      for (int cc = 0; cc < 4; ++cc){
        const int c = half*4 + cc;
        float v[8];
        #pragma unroll
        for (int i=0;i<8;++i) v[i] = invc ? a64[c*8+i]*iv : a64[c*8+i];
        s16x8 hh, rr; split8v(v, hh, rr);
        const int o = r*128 + ((c*16) ^ swz);
        *(s16x8*)&sBH[o] = hh;
        *(s16x8*)&sBH[8192 + o] = rr;
      }
      if (half == 0){
        sAgg2[r][0] = invc ? agg2[(size_t)node*2]*iv   : agg2[(size_t)node*2];
        sAgg2[r][1] = invc ? agg2[(size_t)node*2+1]*iv : agg2[(size_t)node*2+1];
      }
    }
  }
  __syncthreads();

  const int lane  = tid & 63;
  const int wv    = tid >> 6;
  const int colj  = lane & 15;
  const int g     = lane >> 4;
  const int rowA0 = wv*16 + colj;
  const int mrow0 = wv*16 + g*4;

  float a0r[4], a1r[4];
  #pragma unroll
  for (int r=0; r<4; ++r){
    const int m = mrow0 + r;
    a0r[r] = sAgg2[m][0]; a1r[r] = sAgg2[m][1];
  }

  // ---- GEMM1: [64,128] @ W1ext -> [64,192] in two nt-halves ----
  f32x4 acc1[12];
  #pragma unroll
  for (int i=0;i<12;++i) acc1[i] = f32x4{0,0,0,0};
  #pragma unroll
  for (int half = 0; half < 2; ++half){
    f32x4 aR[6];
    #pragma unroll
    for (int i=0;i<6;++i) aR[i] = f32x4{0,0,0,0};
    #pragma unroll
    for (int ks = 0; ks < 4; ++ks){
      const int ch = (ks&1)*4 + g;
      const unsigned char* pH = (ks<2) ? sAh : sBH;
      const unsigned char* pL = (ks<2) ? sAl : (sBH + 8192);
      const int o0 = rowA0*128 + ((ch*16) ^ ((rowA0&7)<<4));
      const f16x8 ah = *(const f16x8*)&pH[o0];
      const f16x8 ar = *(const f16x8*)&pL[o0];
      const f16x8* bh = (const f16x8*)(wf + WOFF_T3) + (ks*12 + half*6)*64 + lane;
      const f16x8* bl = (const f16x8*)(wf + WOFF_T3 + WLO) + (ks*12 + half*6)*64 + lane;
      #pragma unroll
      for (int t = 0; t < 6; ++t){
        const int nt = half*6 + t;
        const f16x8 b1 = bh[t*64];
        const f16x8 b2 = bl[t*64];
        acc1[nt] = MFMAH(ah, b1, acc1[nt]);
        aR[t]    = MFMAH(ar, b1, aR[t]);
        aR[t]    = MFMAH(ah, b2, aR[t]);
      }
    }
    #pragma unroll
    for (int t=0;t<6;++t)
      #pragma unroll
      for (int r=0; r<4; ++r)
        acc1[half*6+t][r] += aR[t][r] * INV2048;
  }
  { // agg cols 64,65 (W rows 128,129) exact fp32
    #pragma unroll
    for (int nt=0; nt<12; ++nt){
      const int j = nt*16 + colj;
      float w0, w1;
      if (j < 128){ w0 = n2w1_tail[j]; w1 = n2w1_tail[128 + j]; }
      else { w0 = n2resw_tail[j-128]; w1 = n2resw_tail[64 + (j-128)]; }
      #pragma unroll
      for (int r=0; r<4; ++r)
        acc1[nt][r] += a0r[r]*w0 + a1r[r]*w1;
    }
  }
  { // fold bias+relu into acc1 hidden part
    #pragma unroll
    for (int nt=0; nt<8; ++nt){
      const float bb = b1[nt*16 + colj];
      #pragma unroll
      for (int r=0; r<4; ++r)
        acc1[nt][r] = fmaxf(acc1[nt][r] + bb, 0.f);
    }
  }

  __syncthreads();   // all reads of sBH done before overwrite with H3

  { // H3 hi (f16) -> LDS (256B rows)
    #pragma unroll
    for (int nt=0; nt<8; ++nt){
      const int j = nt*16 + colj;
      const int co = (j>>3)<<4, wi = (j&7)*2;
      #pragma unroll
      for (int r=0; r<4; ++r){
        const int m = mrow0 + r;
        unsigned short us, ur; split16(acc1[nt][r], us, ur);
        *(unsigned short*)&sBH[m*256 + ((co ^ ((m&7)<<4)) + wi)] = us;
      }
    }
  }
  __syncthreads();

  // ---- GEMM2-hi: acc2 += H3hi@W1 ; acc2R += H3hi@W2 ----
  f32x4 acc2[4], acc2R[4];
  #pragma unroll
  for (int i=0;i<4;++i){ acc2[i] = f32x4{0,0,0,0}; acc2R[i] = f32x4{0,0,0,0}; }
  #pragma unroll
  for (int ks=0; ks<4; ++ks){
    const int ch = ks*4 + g;
    const f16x8 a0 = *(const f16x8*)&sBH[rowA0*256 + ((ch*16) ^ ((rowA0&7)<<4))];
    const f16x8* bh = (const f16x8*)(wf + WOFF_T4) + (ks*4)*64 + lane;
    const f16x8* bl = (const f16x8*)(wf + WOFF_T4 + WLO) + (ks*4)*64 + lane;
    #pragma unroll
    for (int nt = 0; nt < 4; ++nt){
      const f16x8 b1 = bh[nt*64];
      const f16x8 b2 = bl[nt*64];
      acc2[nt]  = MFMAH(a0, b1, acc2[nt]);
      acc2R[nt] = MFMAH(a0, b2, acc2R[nt]);
    }
  }
  __syncthreads();

  { // H3 scaled-residual -> LDS
    #pragma unroll
    for (int nt=0; nt<8; ++nt){
      const int j = nt*16 + colj;
      const int co = (j>>3)<<4, wi = (j&7)*2;
      #pragma unroll
      for (int r=0; r<4; ++r){
        const int m = mrow0 + r;
        unsigned short us, ur; split16(acc1[nt][r], us, ur);
        *(unsigned short*)&sBH[m*256 + ((co ^ ((m&7)<<4)) + wi)] = ur;
      }
    }
  }
  __syncthreads();

  // ---- GEMM2-lo: acc2R += H3res@W1 ; fold ----
  #pragma unroll
  for (int ks=0; ks<4; ++ks){
    const int ch = ks*4 + g;
    const f16x8 a0 = *(const f16x8*)&sBH[rowA0*256 + ((ch*16) ^ ((rowA0&7)<<4))];
    const f16x8* bh = (const f16x8*)(wf + WOFF_T4) + (ks*4)*64 + lane;
    #pragma unroll
    for (int nt = 0; nt < 4; ++nt){
      const f16x8 b1 = bh[nt*64];
      acc2R[nt] = MFMAH(a0, b1, acc2R[nt]);
    }
  }
  #pragma unroll
  for (int nt=0; nt<4; ++nt)
    #pragma unroll
    for (int r=0; r<4; ++r)
      acc2[nt][r] += acc2R[nt][r] * INV2048;

  // ---- epilogue: LN(64) two-pass (np-matching) + residual + "+nodes" ----
  {
    float b2v[4], rbv[4], lgv[4], lbv[4];
    #pragma unroll
    for (int nt=0; nt<4; ++nt){
      const int j = nt*16 + colj;
      b2v[nt] = b2[j]; rbv[nt] = resb[j]; lgv[nt] = lng[j]; lbv[nt] = lnb[j];
    }
    #pragma unroll
    for (int r=0; r<4; ++r){
      const int m = mrow0 + r;
      const int node = nbase + m;
      float v[4]; float sum = 0.f;
      #pragma unroll
      for (int nt=0; nt<4; ++nt){
        const float resi = __fadd_rn(acc1[8+nt][r], rbv[nt]);
        const float hh   = __fadd_rn(acc2[nt][r], b2v[nt]);
        const float xv = __fadd_rn(resi, hh);
        v[nt] = xv; sum += xv;
      }
      #pragma unroll
      for (int mm=1; mm<16; mm<<=1) sum += __shfl_xor(sum, mm, 64);
      const float mean = sum / 64.0f;
      float d[4]; float sq = 0.f;
      #pragma unroll
      for (int nt=0; nt<4; ++nt){
        d[nt] = __fsub_rn(v[nt], mean);
        sq = __fadd_rn(sq, __fmul_rn(d[nt], d[nt]));
      }
      #pragma unroll
      for (int mm=1; mm<16; mm<<=1) sq += __shfl_xor(sq, mm, 64);
      const float var  = sq / 64.0f;
      const float rstd = 1.0f / sqrtf(var + 1e-5f);
      #pragma unroll
      for (int nt=0; nt<4; ++nt){
        const int j = nt*16 + colj;
        const size_t idx = (size_t)node*64 + j;
        const float lnout = __fadd_rn(__fmul_rn(__fmul_rn(d[nt], rstd), lgv[nt]), lbv[nt]);
        nodes[idx] = __fadd_rn(lnout, nodes[idx]);
      }
    }
  }
}

__global__ void k_copy(const float* __restrict__ nodes, float* __restrict__ out){
  const int i = blockIdx.x*256 + threadIdx.x;   // grid exactly NACT*16
  if (i < NACT*16)
    ((float4*)out)[i] = ((const float4*)nodes)[NPAD*16 + i];
}

extern "C" void kernel_launch(void* const* d_in, const int* in_sizes, int n_in,
                              void* d_out, int out_size, void* d_ws, size_t ws_size,
                              hipStream_t stream){
  const float* x       = (const float*)d_in[0];
  const int*   ei      = (const int*)  d_in[1];
  const float* eattr   = (const float*)d_in[2];
  const float* e_res_w = (const float*)d_in[3];
  const float* e_res_b = (const float*)d_in[4];
  const float* e_w1    = (const float*)d_in[5];
  const float* e_b1    = (const float*)d_in[6];
  const float* e_w2    = (const float*)d_in[7];
  const float* e_b2    = (const float*)d_in[8];
  const float* e_ln_g  = (const float*)d_in[9];
  const float* e_ln_b  = (const float*)d_in[10];
  const float* n1_w1   = (const float*)d_in[11];
  const float* n1_b1   = (const float*)d_in[12];
  const float* n1_w2   = (const float*)d_in[13];
  const float* n1_b2   = (const float*)d_in[14];
  const float* n1_ln_g = (const float*)d_in[15];
  const float* n1_ln_b = (const float*)d_in[16];
  const float* n2_res_w= (const float*)d_in[17];
  const float* n2_res_b= (const float*)d_in[18];
  const float* n2_w1   = (const float*)d_in[19];
  const float* n2_b1   = (const float*)d_in[20];
  const float* n2_w2   = (const float*)d_in[21];
  const float* n2_b2   = (const float*)d_in[22];
  const float* n2_ln_g = (const float*)d_in[23];
  const float* n2_ln_b = (const float*)d_in[24];

  if (ws_size < 21364736u) return;

  char* ws = (char*)d_ws;
  float*          nodes = (float*)(ws + 0);             // NN*64 f32
  float*          edges = (float*)(ws + 8388608);       // NEDGE*2 f32
  float*          agg64 = (float*)(ws + 10223616);      // NN*64 f32
  float*          agg2  = (float*)(ws + 18612224);      // NN*2 f32
  int*            cnt   = (int*)(ws + 18874368);
  float*          invc  = (float*)(ws + 19005440);
  unsigned short* wfrag = (unsigned short*)(ws + 19136512);  // ends 21364736
  // fast-path extras
  int*   row_start = (int*)(ws + 21364736);             // NN+1 ints
  int*   fill      = (int*)(ws + 21496064);
  int*   ssrc      = (int*)(ws + 21627136);
  int*   sdst      = (int*)(ws + 22544640);
  int*   seid      = (int*)(ws + 23462144);
  float* medge64   = (float*)(ws + 24379648);           // NEDGE*64 f32
  float* medge2    = (float*)(ws + 83099904);           // NEDGE*2 f32, ends 84934912

  const bool fast = ws_size >= 84934912u;

  k_pack<<<dim3(12,8,5),256,0,stream>>>(e_w1, e_res_w, n1_w1, n1_w2, n2_w1, n2_res_w, n2_w2, wfrag);
  k_init<<<8192,256,0,stream>>>(x, eattr, nodes, edges, cnt);
  k_count<<<896,256,0,stream>>>(ei, cnt);
  k_inv<<<128,256,0,stream>>>(cnt, invc, fast ? fill : cnt /*dummy*/);

  const int* sidx = ei;
  const int* didx = ei + NEDGE;
  if (fast){
    k_scan<<<1,256,0,stream>>>(cnt, row_start);
    k_place<<<896,256,0,stream>>>(ei, row_start, fill, ssrc, sdst, seid);
    k_sortb<<<128,256,0,stream>>>(row_start, seid, ssrc);
    k_perm<<<896,256,0,stream>>>(eattr, seid, edges);
    sidx = ssrc; didx = sdst;
  }

  for (int l = 0; l < NLAY; ++l){
    if (!fast) k_zero_agg<<<8192,256,0,stream>>>(agg64, agg2);
    k_edge<<<3584,256,0,stream>>>(sidx, didx, edges, nodes,
        wfrag + (size_t)l*WLAYER, agg64, agg2,
        fast ? medge64 : nullptr, fast ? medge2 : nullptr,
        e_b1 + l*128, e_w2 + l*256, e_b2 + l*2, e_res_b + l*2, e_ln_g + l*2, e_ln_b + l*2,
        e_w1 + ((size_t)l*130 + 128)*128,
        e_res_w + ((size_t)l*130 + 128)*2,
        n1_w1 + ((size_t)l*66 + 64)*128,
        n1_b1 + l*128, n1_b2 + l*66, n1_ln_g + l*66, n1_ln_b + l*66);
    if (fast) k_agg<<<8192,256,0,stream>>>(medge64, medge2, row_start, cnt, agg64, agg2);
    k_node<<<512,256,0,stream>>>(nodes, agg64, agg2, fast ? nullptr : invc,
        wfrag + (size_t)l*WLAYER,
        n2_b1 + l*128, n2_res_b + l*64, n2_b2 + l*64, n2_ln_g + l*64, n2_ln_b + l*64,
        n2_w1 + ((size_t)l*130 + 128)*128,
        n2_res_w + ((size_t)l*130 + 128)*64);
  }
  k_copy<<<1792,256,0,stream>>>(nodes, (float*)d_out);
}

// Round 8
// 1976.937 us; speedup vs baseline: 1.3868x; 1.2535x over previous
//
#include <hip/hip_runtime.h>

#define NN    32768
#define NACT  28672
#define NPAD  4096
#define NEDGE 229376
#define NLAY  8

// packed weight layout: per layer, W1 plane (f16) then W2 plane (f16, (w-w1)*2048)
#define WOFF_T0 0        // edge W1ext : KT=4 NT=9
#define WOFF_T1 18432    // mlp1 W1    : KT=2 NT=8
#define WOFF_T2 26624    // mlp1 W2ext : KT=4 NT=5
#define WOFF_T3 36864    // node W1ext : KT=4 NT=12
#define WOFF_T4 61440    // node W2    : KT=4 NT=4
#define WLO     69632
#define WLAYER  139264

typedef __attribute__((ext_vector_type(8))) short s16x8;
typedef __attribute__((ext_vector_type(8))) _Float16 f16x8;
typedef __attribute__((ext_vector_type(4))) float f32x4;

#define MFMAH(a,b,c) __builtin_amdgcn_mfma_f32_16x16x32_f16((a),(b),(c),0,0,0)
#define INV2048 4.8828125e-4f

__device__ __forceinline__ unsigned short f2h(float f){
  union { _Float16 h; unsigned short u; } v; v.h = (_Float16)f; return v.u;
}
__device__ __forceinline__ float h2f(unsigned short u){
  union { unsigned short u; _Float16 h; } v; v.u = u; return (float)v.h;
}
// scaled f16 split: a = h + r/2048, |err| ~ 2^-24|a|; denormal-guarded
__device__ __forceinline__ void split16(float a, unsigned short& h, unsigned short& r){
  float hf = 0.f; unsigned short hu = 0;
  if (__builtin_fabsf(a) >= 6.1035156e-5f){ hu = f2h(a); hf = h2f(hu); }
  h = hu;
  r = f2h((a - hf) * 2048.0f);
}
__device__ __forceinline__ void split8v(const float* v, s16x8& h, s16x8& r){
  #pragma unroll
  for (int i=0;i<8;++i){
    unsigned short hh, rr; split16(v[i], hh, rr);
    h[i] = (short)hh; r[i] = (short)rr;
  }
}

// ---------------- weight packing (f16 W1 + scaled-f16 W2 planes) ----------------
__global__ void k_pack(const float* __restrict__ ew1, const float* __restrict__ eresw,
                       const float* __restrict__ n1w1, const float* __restrict__ n1w2,
                       const float* __restrict__ n2w1, const float* __restrict__ n2resw,
                       const float* __restrict__ n2w2,
                       unsigned short* __restrict__ wfrag){
  const int l = blockIdx.y, T = blockIdx.z;
  int KT, NT, off;
  if (T==0){ KT=4; NT=9;  off=WOFF_T0; }
  else if (T==1){ KT=2; NT=8;  off=WOFF_T1; }
  else if (T==2){ KT=4; NT=5;  off=WOFF_T2; }
  else if (T==3){ KT=4; NT=12; off=WOFF_T3; }
  else          { KT=4; NT=4;  off=WOFF_T4; }
  const int f = blockIdx.x*256 + threadIdx.x;
  if (f >= KT*NT*64) return;
  const int lane = f & 63;
  const int fn = f >> 6;
  const int nt = fn % NT, ks = fn / NT;
  const int n  = nt*16 + (lane & 15);
  const int kb = ks*32 + (lane >> 4)*8;
  s16x8 vh, vl;
  #pragma unroll
  for (int i=0;i<8;++i){
    const int k = kb + i;
    float w = 0.f;
    if (T==0){
      if (n < 128)      w = ew1[((size_t)l*130 + k)*128 + n];
      else if (n < 130) w = eresw[((size_t)l*130 + k)*2 + (n-128)];
    } else if (T==1){
      w = n1w1[((size_t)l*66 + k)*128 + n];
    } else if (T==2){
      if (n < 66) w = n1w2[((size_t)l*128 + k)*66 + n];
    } else if (T==3){
      if (n < 128) w = n2w1[((size_t)l*130 + k)*128 + n];
      else         w = n2resw[((size_t)l*130 + k)*64 + (n-128)];
    } else {
      w = n2w2[((size_t)l*128 + k)*64 + n];
    }
    unsigned short hh, rr; split16(w, hh, rr);
    vh[i] = (short)hh; vl[i] = (short)rr;
  }
  *(s16x8*)(wfrag + (size_t)l*WLAYER + off + (size_t)f*8) = vh;
  *(s16x8*)(wfrag + (size_t)l*WLAYER + off + WLO + (size_t)f*8) = vl;
}

// ---------------- init / degree / sort ----------------
__global__ void k_init(const float* __restrict__ x, const float* __restrict__ ea,
                       float* __restrict__ nodes, float* __restrict__ edges,
                       int* __restrict__ cnt){
  const int i = blockIdx.x*256 + threadIdx.x;   // grid = exactly NN*64
  nodes[i] = (i >= NPAD*64) ? x[i - NPAD*64] : 0.f;
  if (i < NEDGE*2) edges[i] = ea[i];
  if (i < NN) cnt[i] = 0;
}

__global__ void k_count(const int* __restrict__ ei, int* __restrict__ cnt){
  const int e = blockIdx.x*256 + threadIdx.x;
  if (e < NEDGE) atomicAdd(&cnt[ei[NEDGE + e]], 1);
}

__global__ void k_inv(const int* __restrict__ cnt, float* __restrict__ invc,
                      int* __restrict__ fill){
  const int n = blockIdx.x*256 + threadIdx.x;
  if (n < NN){ invc[n] = 1.0f / (float)max(cnt[n], 1); fill[n] = 0; }
}

__global__ void k_scan(const int* __restrict__ cnt, int* __restrict__ row_start){
  __shared__ int part[256];
  const int t = threadIdx.x;
  int s = 0;
  for (int i=0;i<128;++i) s += cnt[t*128+i];
  part[t] = s;
  __syncthreads();
  if (t == 0){
    int run = 0;
    for (int i=0;i<256;++i){ const int v = part[i]; part[i] = run; run += v; }
  }
  __syncthreads();
  int base = part[t];
  for (int i=0;i<128;++i){ row_start[t*128+i] = base; base += cnt[t*128+i]; }
  if (t == 255) row_start[NN] = base;
}

__global__ void k_place(const int* __restrict__ ei, const int* __restrict__ row_start,
                        int* __restrict__ fill, int* __restrict__ ssrc,
                        int* __restrict__ sdst, int* __restrict__ seid){
  const int e = blockIdx.x*256 + threadIdx.x;
  if (e >= NEDGE) return;
  const int d = ei[NEDGE + e];
  const int pos = row_start[d] + atomicAdd(&fill[d], 1);
  ssrc[pos] = ei[e];
  sdst[pos] = d;
  seid[pos] = e;
}

// deterministic within-bucket order: insertion sort by eid (deg ~7)
__global__ void k_sortb(const int* __restrict__ row_start,
                        int* __restrict__ seid, int* __restrict__ ssrc){
  const int n = blockIdx.x*256 + threadIdx.x;
  if (n >= NN) return;
  const int rs = row_start[n], re = row_start[n+1];
  for (int i = rs+1; i < re; ++i){
    const int e = seid[i], s = ssrc[i];
    int j = i-1;
    while (j >= rs && seid[j] > e){ seid[j+1]=seid[j]; ssrc[j+1]=ssrc[j]; --j; }
    seid[j+1] = e; ssrc[j+1] = s;
  }
}

// permute edge_attr into sorted order (edges stays sorted all layers)
__global__ void k_perm(const float* __restrict__ ea, const int* __restrict__ seid,
                       float* __restrict__ edges){
  const int e = blockIdx.x*256 + threadIdx.x;
  if (e < NEDGE){
    const int o = seid[e];
    ((float2*)edges)[e] = ((const float2*)ea)[o];
  }
}

__global__ void k_zero_agg(float* __restrict__ agg64, float* __restrict__ agg2){
  const int i = blockIdx.x*256 + threadIdx.x;   // grid exactly NN*64
  agg64[i] = 0.f;
  if (i < NN*2) agg2[i] = 0.f;
}

// CSR aggregation: one wave per node, no atomics; eid-ascending order matches
// np.add.at; true fp32 division matches the reference's "/ cnt".
__global__ __launch_bounds__(256)
void k_agg(const float* __restrict__ medge64, const float* __restrict__ medge2,
           const int* __restrict__ row_start, const int* __restrict__ cnt,
           float* __restrict__ agg64, float* __restrict__ agg2){
  const int n = blockIdx.x*4 + (threadIdx.x >> 6);
  const int lane = threadIdx.x & 63;
  const int rs = row_start[n], re = row_start[n+1];
  const float cf = (float)max(cnt[n], 1);
  float a = 0.f, b = 0.f;
  for (int r = rs; r < re; ++r){
    a = __fadd_rn(a, medge64[(size_t)r*64 + lane]);
    if (lane < 2) b = __fadd_rn(b, medge2[(size_t)r*2 + lane]);
  }
  agg64[(size_t)n*64 + lane] = a / cf;
  if (lane < 2) agg2[(size_t)n*2 + lane] = b / cf;
}

// ---------------- fused edge kernel (64 edges/block): EdgeModel + mlp_1 ----------------
__global__ __launch_bounds__(256,3)
void k_edge(const int* __restrict__ sidx, const int* __restrict__ didx,
            float* __restrict__ edges,
            const float* __restrict__ nodes,
            const unsigned short* __restrict__ wf,
            float* __restrict__ agg64, float* __restrict__ agg2,
            float* __restrict__ medge64, float* __restrict__ medge2,
            const float* __restrict__ eb1, const float* __restrict__ ew2,
            const float* __restrict__ eb2, const float* __restrict__ eresb,
            const float* __restrict__ elng, const float* __restrict__ elnb,
            const float* __restrict__ ew1_tail,   // e_w1 rows 128,129 (stride 128)
            const float* __restrict__ eresw_tail, // e_res_w rows 128,129 (stride 2)
            const float* __restrict__ n1w1_tail,  // n1_w1 rows 64,65 (stride 128)
            const float* __restrict__ n1b1, const float* __restrict__ n1b2,
            const float* __restrict__ n1lng, const float* __restrict__ n1lnb)
{
  __shared__ __align__(16) unsigned char sAh[64*128];  // src f16 hi
  __shared__ __align__(16) unsigned char sAl[64*128];  // src f16 scaled-res
  __shared__ __align__(16) unsigned char sBH[64*256];  // dst hi[0:8K) res[8K:16K); later H2 (256B rows)
  __shared__ float sEold[64][2];
  __shared__ int   sCol[64];

  const int tid = threadIdx.x;
  const int ebase = blockIdx.x * 64;

  { // staging: 2 threads per row; tid<128 src, tid>=128 dst
    const int r = (tid & 127) >> 1;
    const int half = tid & 1;
    const int es = ebase + r;
    const int swz = (r & 7) << 4;
    if (tid < 128){
      const int sn = sidx[es];
      const float4* sp = (const float4*)(nodes + (size_t)sn*64);
      #pragma unroll
      for (int cc = 0; cc < 4; ++cc){
        const int c = half*4 + cc;
        const float4 f0 = sp[2*c], f1 = sp[2*c+1];
        float v[8] = {f0.x,f0.y,f0.z,f0.w,f1.x,f1.y,f1.z,f1.w};
        s16x8 hh, rr; split8v(v, hh, rr);
        const int o = r*128 + ((c*16) ^ swz);
        *(s16x8*)&sAh[o] = hh;
        *(s16x8*)&sAl[o] = rr;
      }
    } else {
      const int dn = didx[es];
      const float4* dp = (const float4*)(nodes + (size_t)dn*64);
      #pragma unroll
      for (int cc = 0; cc < 4; ++cc){
        const int c = half*4 + cc;
        const float4 f0 = dp[2*c], f1 = dp[2*c+1];
        float v[8] = {f0.x,f0.y,f0.z,f0.w,f1.x,f1.y,f1.z,f1.w};
        s16x8 hh, rr; split8v(v, hh, rr);
        const int o = r*128 + ((c*16) ^ swz);
        *(s16x8*)&sBH[o] = hh;
        *(s16x8*)&sBH[8192 + o] = rr;
      }
      if (half == 0){
        const float2 ev = *(const float2*)(edges + (size_t)es*2);
        sEold[r][0] = ev.x; sEold[r][1] = ev.y;
        sCol[r] = dn;
      }
    }
  }
  __syncthreads();

  const int lane  = tid & 63;
  const int wv    = tid >> 6;
  const int colj  = lane & 15;
  const int g     = lane >> 4;
  const int rowA0 = wv*16 + colj;      // A-frag row
  const int mrow0 = wv*16 + g*4;       // C/D row base (add r)

  float e0r[4], e1r[4];
  #pragma unroll
  for (int r=0; r<4; ++r){
    const int m = mrow0 + r;
    e0r[r] = sEold[m][0]; e1r[r] = sEold[m][1];
  }

  // ---- phase 1: Hext[64,144] = X[64,128] @ W1ext + e-cols fp32 rank-2 ----
  // split into two nt-halves (5 + 4) to halve temp-accumulator live range;
  // per-nt MFMA and fold order identical to the monolithic version (bitwise same)
  f32x4 acc1[9];
  #pragma unroll
  for (int i=0;i<9;++i) acc1[i] = f32x4{0,0,0,0};
  {
    #pragma unroll
    for (int half = 0; half < 2; ++half){
      const int nt0 = half*5;
      const int NTH = half ? 4 : 5;
      f32x4 accR[5];
      #pragma unroll
      for (int i=0;i<5;++i) accR[i] = f32x4{0,0,0,0};
      #pragma unroll
      for (int ks = 0; ks < 4; ++ks){
        const int ch = (ks&1)*4 + g;
        const unsigned char* pH = (ks<2) ? sAh : sBH;
        const unsigned char* pL = (ks<2) ? sAl : (sBH + 8192);
        const int o0 = rowA0*128 + ((ch*16) ^ ((rowA0&7)<<4));
        const f16x8 ah = *(const f16x8*)&pH[o0];
        const f16x8 ar = *(const f16x8*)&pL[o0];
        const f16x8* bh = (const f16x8*)(wf + WOFF_T0) + (ks*9 + nt0)*64 + lane;
        const f16x8* bl = (const f16x8*)(wf + WOFF_T0 + WLO) + (ks*9 + nt0)*64 + lane;
        #pragma unroll
        for (int t = 0; t < 5; ++t){
          if (t >= NTH) break;
          const f16x8 b1 = bh[t*64];
          const f16x8 b2 = bl[t*64];
          acc1[nt0+t] = MFMAH(ah, b1, acc1[nt0+t]);
          accR[t]     = MFMAH(ar, b1, accR[t]);
          accR[t]     = MFMAH(ah, b2, accR[t]);
        }
      }
      #pragma unroll
      for (int t=0; t<5; ++t){
        if (t >= NTH) break;
        #pragma unroll
        for (int r=0; r<4; ++r)
          acc1[nt0+t][r] += accR[t][r] * INV2048;
      }
    }
    #pragma unroll
    for (int nt=0; nt<9; ++nt){
      const int j = nt*16 + colj;
      float w0, w1;
      if (nt < 8){ w0 = ew1_tail[j]; w1 = ew1_tail[128 + j]; }
      else { w0 = (colj<2) ? eresw_tail[colj] : 0.f; w1 = (colj<2) ? eresw_tail[2+colj] : 0.f; }
      #pragma unroll
      for (int r=0; r<4; ++r)
        acc1[nt][r] += e0r[r]*w0 + e1r[r]*w1;
    }
  }

  // ---- phase 2: edge head (N=2) + LN(2) + residual ----
  float enew[4][2];
  {
    float2 w2v[8]; float b1v[8];
    #pragma unroll
    for (int nt=0; nt<8; ++nt){
      const int j = nt*16 + colj;
      w2v[nt] = *(const float2*)(ew2 + (size_t)j*2);
      b1v[nt] = eb1[j];
    }
    const float rb0 = eresb[0], rb1 = eresb[1];
    const float g0 = elng[0], g1 = elng[1], lb0 = elnb[0], lb1 = elnb[1];
    const float bb0 = eb2[0], bb1 = eb2[1];
    #pragma unroll
    for (int r=0; r<4; ++r){
      float v0 = 0.f, v1 = 0.f;
      #pragma unroll
      for (int nt=0; nt<8; ++nt){
        const float h = fmaxf(acc1[nt][r] + b1v[nt], 0.f);
        v0 = fmaf(h, w2v[nt].x, v0);
        v1 = fmaf(h, w2v[nt].y, v1);
      }
      const float resv = acc1[8][r];
      if (colj == 0) v0 += resv + rb0;
      if (colj == 1) v1 += resv + rb1;
      #pragma unroll
      for (int mm=1; mm<16; mm<<=1){
        v0 += __shfl_xor(v0, mm, 64);
        v1 += __shfl_xor(v1, mm, 64);
      }
      v0 += bb0; v1 += bb1;
      // LayerNorm(2) with np-matching rounding
      const float m2 = __fmul_rn(__fadd_rn(v0, v1), 0.5f);
      const float d0 = __fsub_rn(v0, m2);
      const float d1 = __fsub_rn(v1, m2);
      const float var = __fmul_rn(__fadd_rn(__fmul_rn(d0,d0), __fmul_rn(d1,d1)), 0.5f);
      const float rstd = 1.0f / sqrtf(var + 1e-5f);
      const int m = mrow0 + r;
      const float e0 = __fadd_rn(__fadd_rn(__fmul_rn(__fmul_rn(d0, rstd), g0), lb0), e0r[r]);
      const float e1 = __fadd_rn(__fadd_rn(__fmul_rn(__fmul_rn(d1, rstd), g1), lb1), e1r[r]);
      enew[r][0] = e0; enew[r][1] = e1;
      if (colj == 0)
        *(float2*)(edges + (size_t)(ebase + m)*2) = make_float2(e0, e1);
    }
  }

  // ---- phase 3: H2[64,128] = src[64,64] @ n1_w1 (+ fp32 rank-2 for e) ----
  // temp accumulator split into two nt-halves (4 + 4); bitwise same per nt
  f32x4 acc2[8];
  #pragma unroll
  for (int i=0;i<8;++i) acc2[i] = f32x4{0,0,0,0};
  {
    #pragma unroll
    for (int half = 0; half < 2; ++half){
      const int nt0 = half*4;
      f32x4 accR[4];
      #pragma unroll
      for (int i=0;i<4;++i) accR[i] = f32x4{0,0,0,0};
      #pragma unroll
      for (int ks=0; ks<2; ++ks){
        const int ch = ks*4 + g;
        const int o0 = rowA0*128 + ((ch*16) ^ ((rowA0&7)<<4));
        const f16x8 ah = *(const f16x8*)&sAh[o0];
        const f16x8 ar = *(const f16x8*)&sAl[o0];
        const f16x8* bh = (const f16x8*)(wf + WOFF_T1) + (ks*8 + nt0)*64 + lane;
        const f16x8* bl = (const f16x8*)(wf + WOFF_T1 + WLO) + (ks*8 + nt0)*64 + lane;
        #pragma unroll
        for (int t = 0; t < 4; ++t){
          const f16x8 b1 = bh[t*64];
          const f16x8 b2 = bl[t*64];
          acc2[nt0+t] = MFMAH(ah, b1, acc2[nt0+t]);
          accR[t]     = MFMAH(ar, b1, accR[t]);
          accR[t]     = MFMAH(ah, b2, accR[t]);
        }
      }
      #pragma unroll
      for (int t=0; t<4; ++t)
        #pragma unroll
        for (int r=0; r<4; ++r)
          acc2[nt0+t][r] += accR[t][r] * INV2048;
    }
  }
  {
    #pragma unroll
    for (int nt=0; nt<8; ++nt){
      const int j = nt*16 + colj;
      const float w64 = n1w1_tail[j];
      const float w65 = n1w1_tail[128 + j];
      const float bb = n1b1[j];
      #pragma unroll
      for (int r=0; r<4; ++r){
        float h = acc2[nt][r] + enew[r][0]*w64 + enew[r][1]*w65 + bb;
        acc2[nt][r] = fmaxf(h, 0.f);
      }
    }
  }

  __syncthreads();   // all phase-1 reads of sBH done before overwrite

  // ---- phase 4a: H2 hi (f16) -> LDS (256B rows over sBH) ----
  {
    #pragma unroll
    for (int nt=0; nt<8; ++nt){
      const int j = nt*16 + colj;
      const int co = (j>>3)<<4, wi = (j&7)*2;
      #pragma unroll
      for (int r=0; r<4; ++r){
        const int m = mrow0 + r;
        unsigned short us, ur; split16(acc2[nt][r], us, ur);
        *(unsigned short*)&sBH[m*256 + ((co ^ ((m&7)<<4)) + wi)] = us;
      }
    }
  }
  __syncthreads();

  // ---- phase 4b-hi: acc3 += H2hi@W1 ; acc3R += H2hi@W2 ----
  f32x4 acc3[5], acc3R[5];
  #pragma unroll
  for (int i=0;i<5;++i){ acc3[i] = f32x4{0,0,0,0}; acc3R[i] = f32x4{0,0,0,0}; }
  #pragma unroll
  for (int ks=0; ks<4; ++ks){
    const int ch = ks*4 + g;
    const f16x8 a0 = *(const f16x8*)&sBH[rowA0*256 + ((ch*16) ^ ((rowA0&7)<<4))];
    const f16x8* bh = (const f16x8*)(wf + WOFF_T2) + (ks*5)*64 + lane;
    const f16x8* bl = (const f16x8*)(wf + WOFF_T2 + WLO) + (ks*5)*64 + lane;
    #pragma unroll
    for (int nt = 0; nt < 5; ++nt){
      const f16x8 b1 = bh[nt*64];
      const f16x8 b2 = bl[nt*64];
      acc3[nt]  = MFMAH(a0, b1, acc3[nt]);
      acc3R[nt] = MFMAH(a0, b2, acc3R[nt]);
    }
  }
  __syncthreads();

  // ---- phase 4a': H2 scaled-residual -> LDS ----
  {
    #pragma unroll
    for (int nt=0; nt<8; ++nt){
      const int j = nt*16 + colj;
      const int co = (j>>3)<<4, wi = (j&7)*2;
      #pragma unroll
      for (int r=0; r<4; ++r){
        const int m = mrow0 + r;
        unsigned short us, ur; split16(acc2[nt][r], us, ur);
        *(unsigned short*)&sBH[m*256 + ((co ^ ((m&7)<<4)) + wi)] = ur;
      }
    }
  }
  __syncthreads();

  // ---- phase 4b-lo: acc3R += H2res@W1 ; fold ----
  #pragma unroll
  for (int ks=0; ks<4; ++ks){
    const int ch = ks*4 + g;
    const f16x8 a0 = *(const f16x8*)&sBH[rowA0*256 + ((ch*16) ^ ((rowA0&7)<<4))];
    const f16x8* bh = (const f16x8*)(wf + WOFF_T2) + (ks*5)*64 + lane;
    #pragma unroll
    for (int nt = 0; nt < 5; ++nt){
      const f16x8 b1 = bh[nt*64];
      acc3R[nt] = MFMAH(a0, b1, acc3R[nt]);
    }
  }
  #pragma unroll
  for (int nt=0; nt<5; ++nt)
    #pragma unroll
    for (int r=0; r<4; ++r)
      acc3[nt][r] += acc3R[nt][r] * INV2048;

  // ---- phase 4c: LN(66) two-pass (np-matching) + emit ----
  {
    float b2v[5], lgv[5], lbv[5];
    #pragma unroll
    for (int nt=0; nt<5; ++nt){
      const int j = nt*16 + colj;
      const bool ok = j < 66;
      b2v[nt] = ok ? n1b2[j]  : 0.f;
      lgv[nt] = ok ? n1lng[j] : 0.f;
      lbv[nt] = ok ? n1lnb[j] : 0.f;
    }
    #pragma unroll
    for (int r=0; r<4; ++r){
      const int m = mrow0 + r;
      float v[5]; float sum = 0.f;
      #pragma unroll
      for (int nt=0; nt<5; ++nt){
        const int j = nt*16 + colj;
        float xv = 0.f;
        if (j < 64){
          const int o = m*128 + (((((j>>3)<<4)) ^ ((m&7)<<4)) + (j&7)*2);
          const float resd = h2f(*(const unsigned short*)&sAh[o])
                           + h2f(*(const unsigned short*)&sAl[o]) * INV2048;
          xv = __fadd_rn(resd, __fadd_rn(acc3[nt][r], b2v[nt]));
        } else if (j < 66){
          xv = __fadd_rn(enew[r][j-64], __fadd_rn(acc3[nt][r], b2v[nt]));
        }
        v[nt] = xv;
        sum += xv;
      }
      #pragma unroll
      for (int mm=1; mm<16; mm<<=1) sum += __shfl_xor(sum, mm, 64);
      const float mean = sum / 66.0f;
      float d[5]; float sq = 0.f;
      #pragma unroll
      for (int nt=0; nt<5; ++nt){
        const int j = nt*16 + colj;
        d[nt] = (j < 66) ? __fsub_rn(v[nt], mean) : 0.f;
        sq = __fadd_rn(sq, __fmul_rn(d[nt], d[nt]));
      }
      #pragma unroll
      for (int mm=1; mm<16; mm<<=1) sq += __shfl_xor(sq, mm, 64);
      const float var  = sq / 66.0f;
      const float rstd = 1.0f / sqrtf(var + 1e-5f);
      if (medge64){
        float* m64 = medge64 + (size_t)(ebase + m)*64;
        #pragma unroll
        for (int nt=0; nt<4; ++nt)
          m64[nt*16 + colj] = __fadd_rn(__fmul_rn(__fmul_rn(d[nt], rstd), lgv[nt]), lbv[nt]);
        if (colj < 2)
          medge2[(size_t)(ebase + m)*2 + colj] =
            __fadd_rn(__fmul_rn(__fmul_rn(d[4], rstd), lgv[4]), lbv[4]);
      } else {
        float* a64 = agg64 + (size_t)sCol[m]*64;
        #pragma unroll
        for (int nt=0; nt<4; ++nt)
          atomicAdd(a64 + nt*16 + colj, __fadd_rn(__fmul_rn(__fmul_rn(d[nt], rstd), lgv[nt]), lbv[nt]));
        if (colj < 2)
          atomicAdd(agg2 + (size_t)sCol[m]*2 + colj,
                    __fadd_rn(__fmul_rn(__fmul_rn(d[4], rstd), lgv[4]), lbv[4]));
      }
    }
  }
}

// ---------------- node kernel (64 nodes/block): NodeModel.mlp_2 ----------------
__global__ __launch_bounds__(256,3)
void k_node(float* __restrict__ nodes,
            const float* __restrict__ agg64, const float* __restrict__ agg2,
            const float* __restrict__ invc,
            const unsigned short* __restrict__ wf,
            const float* __restrict__ b1, const float* __restrict__ resb,
            const float* __restrict__ b2, const float* __restrict__ lng,
            const float* __restrict__ lnb,
            const float* __restrict__ n2w1_tail,   // n2_w1 rows 128,129 (stride 128)
            const float* __restrict__ n2resw_tail) // n2_res_w rows 128,129 (stride 64)
{
  __shared__ __align__(16) unsigned char sAh[64*128];  // nodes f16 hi
  __shared__ __align__(16) unsigned char sAl[64*128];  // nodes f16 scaled-res
  __shared__ __align__(16) unsigned char sBH[64*256];  // agg hi/res; later H3 (256B rows)
  __shared__ float sAgg2[64][2];

  const int tid = threadIdx.x;
  const int nbase = blockIdx.x * 64;

  { // staging: 2 threads per row
    const int r = (tid & 127) >> 1;
    const int half = tid & 1;
    const int node = nbase + r;
    const int swz = (r & 7) << 4;
    if (tid < 128){
      const float4* sp = (const float4*)(nodes + (size_t)node*64);
      #pragma unroll
      for (int cc = 0; cc < 4; ++cc){
        const int c = half*4 + cc;
        const float4 f0 = sp[2*c], f1 = sp[2*c+1];
        float v[8] = {f0.x,f0.y,f0.z,f0.w,f1.x,f1.y,f1.z,f1.w};
        s16x8 hh, rr; split8v(v, hh, rr);
        const int o = r*128 + ((c*16) ^ swz);
        *(s16x8*)&sAh[o] = hh;
        *(s16x8*)&sAl[o] = rr;
      }
    } else {
      const float iv = invc ? invc[node] : 1.0f;
      const float* a64 = agg64 + (size_t)node*64;
      #pragma unroll
      for (int cc = 0; cc < 4; ++cc){
        const int c = half*4 + cc;
        float v[8];
        #pragma unroll
        for (int i=0;i<8;++i) v[i] = invc ? a64[c*8+i]*iv : a64[c*8+i];
        s16x8 hh, rr; split8v(v, hh, rr);
        const int o = r*128 + ((c*16) ^ swz);
        *(s16x8*)&sBH[o] = hh;
        *(s16x8*)&sBH[8192 + o] = rr;
      }
      if (half == 0){
        sAgg2[r][0] = invc ? agg2[(size_t)node*2]*iv   : agg2[(size_t)node*2];
        sAgg2[r][1] = invc ? agg2[(size_t)node*2+1]*iv : agg2[(size_t)node*2+1];
      }
    }
  }
  __syncthreads();

  const int lane  = tid & 63;
  const int wv    = tid >> 6;
  const int colj  = lane & 15;
  const int g     = lane >> 4;
  const int rowA0 = wv*16 + colj;
  const int mrow0 = wv*16 + g*4;

  float a0r[4], a1r[4];
  #pragma unroll
  for (int r=0; r<4; ++r){
    const int m = mrow0 + r;
    a0r[r] = sAgg2[m][0]; a1r[r] = sAgg2[m][1];
  }

  // ---- GEMM1: [64,128] @ W1ext -> [64,192] in two nt-halves ----
  f32x4 acc1[12];
  #pragma unroll
  for (int i=0;i<12;++i) acc1[i] = f32x4{0,0,0,0};
  #pragma unroll
  for (int half = 0; half < 2; ++half){
    f32x4 aR[6];
    #pragma unroll
    for (int i=0;i<6;++i) aR[i] = f32x4{0,0,0,0};
    #pragma unroll
    for (int ks = 0; ks < 4; ++ks){
      const int ch = (ks&1)*4 + g;
      const unsigned char* pH = (ks<2) ? sAh : sBH;
      const unsigned char* pL = (ks<2) ? sAl : (sBH + 8192);
      const int o0 = rowA0*128 + ((ch*16) ^ ((rowA0&7)<<4));
      const f16x8 ah = *(const f16x8*)&pH[o0];
      const f16x8 ar = *(const f16x8*)&pL[o0];
      const f16x8* bh = (const f16x8*)(wf + WOFF_T3) + (ks*12 + half*6)*64 + lane;
      const f16x8* bl = (const f16x8*)(wf + WOFF_T3 + WLO) + (ks*12 + half*6)*64 + lane;
      #pragma unroll
      for (int t = 0; t < 6; ++t){
        const int nt = half*6 + t;
        const f16x8 b1 = bh[t*64];
        const f16x8 b2 = bl[t*64];
        acc1[nt] = MFMAH(ah, b1, acc1[nt]);
        aR[t]    = MFMAH(ar, b1, aR[t]);
        aR[t]    = MFMAH(ah, b2, aR[t]);
      }
    }
    #pragma unroll
    for (int t=0;t<6;++t)
      #pragma unroll
      for (int r=0; r<4; ++r)
        acc1[half*6+t][r] += aR[t][r] * INV2048;
  }
  { // agg cols 64,65 (W rows 128,129) exact fp32
    #pragma unroll
    for (int nt=0; nt<12; ++nt){
      const int j = nt*16 + colj;
      float w0, w1;
      if (j < 128){ w0 = n2w1_tail[j]; w1 = n2w1_tail[128 + j]; }
      else { w0 = n2resw_tail[j-128]; w1 = n2resw_tail[64 + (j-128)]; }
      #pragma unroll
      for (int r=0; r<4; ++r)
        acc1[nt][r] += a0r[r]*w0 + a1r[r]*w1;
    }
  }
  { // fold bias+relu into acc1 hidden part
    #pragma unroll
    for (int nt=0; nt<8; ++nt){
      const float bb = b1[nt*16 + colj];
      #pragma unroll
      for (int r=0; r<4; ++r)
        acc1[nt][r] = fmaxf(acc1[nt][r] + bb, 0.f);
    }
  }

  __syncthreads();   // all reads of sBH done before overwrite with H3

  { // H3 hi (f16) -> LDS (256B rows)
    #pragma unroll
    for (int nt=0; nt<8; ++nt){
      const int j = nt*16 + colj;
      const int co = (j>>3)<<4, wi = (j&7)*2;
      #pragma unroll
      for (int r=0; r<4; ++r){
        const int m = mrow0 + r;
        unsigned short us, ur; split16(acc1[nt][r], us, ur);
        *(unsigned short*)&sBH[m*256 + ((co ^ ((m&7)<<4)) + wi)] = us;
      }
    }
  }
  __syncthreads();

  // ---- GEMM2-hi: acc2 += H3hi@W1 ; acc2R += H3hi@W2 ----
  f32x4 acc2[4], acc2R[4];
  #pragma unroll
  for (int i=0;i<4;++i){ acc2[i] = f32x4{0,0,0,0}; acc2R[i] = f32x4{0,0,0,0}; }
  #pragma unroll
  for (int ks=0; ks<4; ++ks){
    const int ch = ks*4 + g;
    const f16x8 a0 = *(const f16x8*)&sBH[rowA0*256 + ((ch*16) ^ ((rowA0&7)<<4))];
    const f16x8* bh = (const f16x8*)(wf + WOFF_T4) + (ks*4)*64 + lane;
    const f16x8* bl = (const f16x8*)(wf + WOFF_T4 + WLO) + (ks*4)*64 + lane;
    #pragma unroll
    for (int nt = 0; nt < 4; ++nt){
      const f16x8 b1 = bh[nt*64];
      const f16x8 b2 = bl[nt*64];
      acc2[nt]  = MFMAH(a0, b1, acc2[nt]);
      acc2R[nt] = MFMAH(a0, b2, acc2R[nt]);
    }
  }
  __syncthreads();

  { // H3 scaled-residual -> LDS
    #pragma unroll
    for (int nt=0; nt<8; ++nt){
      const int j = nt*16 + colj;
      const int co = (j>>3)<<4, wi = (j&7)*2;
      #pragma unroll
      for (int r=0; r<4; ++r){
        const int m = mrow0 + r;
        unsigned short us, ur; split16(acc1[nt][r], us, ur);
        *(unsigned short*)&sBH[m*256 + ((co ^ ((m&7)<<4)) + wi)] = ur;
      }
    }
  }
  __syncthreads();

  // ---- GEMM2-lo: acc2R += H3res@W1 ; fold ----
  #pragma unroll
  for (int ks=0; ks<4; ++ks){
    const int ch = ks*4 + g;
    const f16x8 a0 = *(const f16x8*)&sBH[rowA0*256 + ((ch*16) ^ ((rowA0&7)<<4))];
    const f16x8* bh = (const f16x8*)(wf + WOFF_T4) + (ks*4)*64 + lane;
    #pragma unroll
    for (int nt = 0; nt < 4; ++nt){
      const f16x8 b1 = bh[nt*64];
      acc2R[nt] = MFMAH(a0, b1, acc2R[nt]);
    }
  }
  #pragma unroll
  for (int nt=0; nt<4; ++nt)
    #pragma unroll
    for (int r=0; r<4; ++r)
      acc2[nt][r] += acc2R[nt][r] * INV2048;

  // ---- epilogue: LN(64) two-pass (np-matching) + residual + "+nodes" ----
  {
    float b2v[4], rbv[4], lgv[4], lbv[4];
    #pragma unroll
    for (int nt=0; nt<4; ++nt){
      const int j = nt*16 + colj;
      b2v[nt] = b2[j]; rbv[nt] = resb[j]; lgv[nt] = lng[j]; lbv[nt] = lnb[j];
    }
    #pragma unroll
    for (int r=0; r<4; ++r){
      const int m = mrow0 + r;
      const int node = nbase + m;
      float v[4]; float sum = 0.f;
      #pragma unroll
      for (int nt=0; nt<4; ++nt){
        const float resi = __fadd_rn(acc1[8+nt][r], rbv[nt]);
        const float hh   = __fadd_rn(acc2[nt][r], b2v[nt]);
        const float xv = __fadd_rn(resi, hh);
        v[nt] = xv; sum += xv;
      }
      #pragma unroll
      for (int mm=1; mm<16; mm<<=1) sum += __shfl_xor(sum, mm, 64);
      const float mean = sum / 64.0f;
      float d[4]; float sq = 0.f;
      #pragma unroll
      for (int nt=0; nt<4; ++nt){
        d[nt] = __fsub_rn(v[nt], mean);
        sq = __fadd_rn(sq, __fmul_rn(d[nt], d[nt]));
      }
      #pragma unroll
      for (int mm=1; mm<16; mm<<=1) sq += __shfl_xor(sq, mm, 64);
      const float var  = sq / 64.0f;
      const float rstd = 1.0f / sqrtf(var + 1e-5f);
      #pragma unroll
      for (int nt=0; nt<4; ++nt){
        const int j = nt*16 + colj;
        const size_t idx = (size_t)node*64 + j;
        const float lnout = __fadd_rn(__fmul_rn(__fmul_rn(d[nt], rstd), lgv[nt]), lbv[nt]);
        nodes[idx] = __fadd_rn(lnout, nodes[idx]);
      }
    }
  }
}

__global__ void k_copy(const float* __restrict__ nodes, float* __restrict__ out){
  const int i = blockIdx.x*256 + threadIdx.x;   // grid exactly NACT*16
  if (i < NACT*16)
    ((float4*)out)[i] = ((const float4*)nodes)[NPAD*16 + i];
}

extern "C" void kernel_launch(void* const* d_in, const int* in_sizes, int n_in,
                              void* d_out, int out_size, void* d_ws, size_t ws_size,
                              hipStream_t stream){
  const float* x       = (const float*)d_in[0];
  const int*   ei      = (const int*)  d_in[1];
  const float* eattr   = (const float*)d_in[2];
  const float* e_res_w = (const float*)d_in[3];
  const float* e_res_b = (const float*)d_in[4];
  const float* e_w1    = (const float*)d_in[5];
  const float* e_b1    = (const float*)d_in[6];
  const float* e_w2    = (const float*)d_in[7];
  const float* e_b2    = (const float*)d_in[8];
  const float* e_ln_g  = (const float*)d_in[9];
  const float* e_ln_b  = (const float*)d_in[10];
  const float* n1_w1   = (const float*)d_in[11];
  const float* n1_b1   = (const float*)d_in[12];
  const float* n1_w2   = (const float*)d_in[13];
  const float* n1_b2   = (const float*)d_in[14];
  const float* n1_ln_g = (const float*)d_in[15];
  const float* n1_ln_b = (const float*)d_in[16];
  const float* n2_res_w= (const float*)d_in[17];
  const float* n2_res_b= (const float*)d_in[18];
  const float* n2_w1   = (const float*)d_in[19];
  const float* n2_b1   = (const float*)d_in[20];
  const float* n2_w2   = (const float*)d_in[21];
  const float* n2_b2   = (const float*)d_in[22];
  const float* n2_ln_g = (const float*)d_in[23];
  const float* n2_ln_b = (const float*)d_in[24];

  if (ws_size < 21364736u) return;

  char* ws = (char*)d_ws;
  float*          nodes = (float*)(ws + 0);             // NN*64 f32
  float*          edges = (float*)(ws + 8388608);       // NEDGE*2 f32
  float*          agg64 = (float*)(ws + 10223616);      // NN*64 f32
  float*          agg2  = (float*)(ws + 18612224);      // NN*2 f32
  int*            cnt   = (int*)(ws + 18874368);
  float*          invc  = (float*)(ws + 19005440);
  unsigned short* wfrag = (unsigned short*)(ws + 19136512);  // ends 21364736
  // fast-path extras
  int*   row_start = (int*)(ws + 21364736);             // NN+1 ints
  int*   fill      = (int*)(ws + 21496064);
  int*   ssrc      = (int*)(ws + 21627136);
  int*   sdst      = (int*)(ws + 22544640);
  int*   seid      = (int*)(ws + 23462144);
  float* medge64   = (float*)(ws + 24379648);           // NEDGE*64 f32
  float* medge2    = (float*)(ws + 83099904);           // NEDGE*2 f32, ends 84934912

  const bool fast = ws_size >= 84934912u;

  k_pack<<<dim3(12,8,5),256,0,stream>>>(e_w1, e_res_w, n1_w1, n1_w2, n2_w1, n2_res_w, n2_w2, wfrag);
  k_init<<<8192,256,0,stream>>>(x, eattr, nodes, edges, cnt);
  k_count<<<896,256,0,stream>>>(ei, cnt);
  k_inv<<<128,256,0,stream>>>(cnt, invc, fast ? fill : cnt /*dummy*/);

  const int* sidx = ei;
  const int* didx = ei + NEDGE;
  if (fast){
    k_scan<<<1,256,0,stream>>>(cnt, row_start);
    k_place<<<896,256,0,stream>>>(ei, row_start, fill, ssrc, sdst, seid);
    k_sortb<<<128,256,0,stream>>>(row_start, seid, ssrc);
    k_perm<<<896,256,0,stream>>>(eattr, seid, edges);
    sidx = ssrc; didx = sdst;
  }

  for (int l = 0; l < NLAY; ++l){
    if (!fast) k_zero_agg<<<8192,256,0,stream>>>(agg64, agg2);
    k_edge<<<3584,256,0,stream>>>(sidx, didx, edges, nodes,
        wfrag + (size_t)l*WLAYER, agg64, agg2,
        fast ? medge64 : nullptr, fast ? medge2 : nullptr,
        e_b1 + l*128, e_w2 + l*256, e_b2 + l*2, e_res_b + l*2, e_ln_g + l*2, e_ln_b + l*2,
        e_w1 + ((size_t)l*130 + 128)*128,
        e_res_w + ((size_t)l*130 + 128)*2,
        n1_w1 + ((size_t)l*66 + 64)*128,
        n1_b1 + l*128, n1_b2 + l*66, n1_ln_g + l*66, n1_ln_b + l*66);
    if (fast) k_agg<<<8192,256,0,stream>>>(medge64, medge2, row_start, cnt, agg64, agg2);
    k_node<<<512,256,0,stream>>>(nodes, agg64, agg2, fast ? nullptr : invc,
        wfrag + (size_t)l*WLAYER,
        n2_b1 + l*128, n2_res_b + l*64, n2_b2 + l*64, n2_ln_g + l*64, n2_ln_b + l*64,
        n2_w1 + ((size_t)l*130 + 128)*128,
        n2_res_w + ((size_t)l*130 + 128)*64);
  }
  k_copy<<<1792,256,0,stream>>>(nodes, (float*)d_out);
}

// Round 9
// 1364.863 us; speedup vs baseline: 2.0086x; 1.4485x over previous
//
#include <hip/hip_runtime.h>

#define NN    32768
#define NACT  28672
#define NPAD  4096
#define NEDGE 229376
#define NLAY  8

// packed weight layout: per layer, W1 plane (f16) then W2 plane (f16, (w-w1)*2048)
#define WOFF_T0 0        // edge W1ext : KT=4 NT=9
#define WOFF_T1 18432    // mlp1 W1    : KT=2 NT=8
#define WOFF_T2 26624    // mlp1 W2ext : KT=4 NT=5
#define WOFF_T3 36864    // node W1ext : KT=4 NT=12
#define WOFF_T4 61440    // node W2    : KT=4 NT=4
#define WLO     69632
#define WLAYER  139264

typedef __attribute__((ext_vector_type(8))) short s16x8;
typedef __attribute__((ext_vector_type(8))) _Float16 f16x8;
typedef __attribute__((ext_vector_type(4))) float f32x4;
typedef unsigned short ushort_t;

#define MFMAH(a,b,c) __builtin_amdgcn_mfma_f32_16x16x32_f16((a),(b),(c),0,0,0)
#define INV2048 4.8828125e-4f

__device__ __forceinline__ unsigned short f2h(float f){
  union { _Float16 h; unsigned short u; } v; v.h = (_Float16)f; return v.u;
}
__device__ __forceinline__ float h2f(unsigned short u){
  union { unsigned short u; _Float16 h; } v; v.u = u; return (float)v.h;
}
// scaled f16 split: a = h + r/2048, |err| ~ 2^-24|a|; denormal-guarded
__device__ __forceinline__ void split16(float a, unsigned short& h, unsigned short& r){
  float hf = 0.f; unsigned short hu = 0;
  if (__builtin_fabsf(a) >= 6.1035156e-5f){ hu = f2h(a); hf = h2f(hu); }
  h = hu;
  r = f2h((a - hf) * 2048.0f);
}
__device__ __forceinline__ void split8v(const float* v, s16x8& h, s16x8& r){
  #pragma unroll
  for (int i=0;i<8;++i){
    unsigned short hh, rr; split16(v[i], hh, rr);
    h[i] = (short)hh; r[i] = (short)rr;
  }
}

// ---------------- weight packing (f16 W1 + scaled-f16 W2 planes) ----------------
__global__ void k_pack(const float* __restrict__ ew1, const float* __restrict__ eresw,
                       const float* __restrict__ n1w1, const float* __restrict__ n1w2,
                       const float* __restrict__ n2w1, const float* __restrict__ n2resw,
                       const float* __restrict__ n2w2,
                       unsigned short* __restrict__ wfrag){
  const int l = blockIdx.y, T = blockIdx.z;
  int KT, NT, off;
  if (T==0){ KT=4; NT=9;  off=WOFF_T0; }
  else if (T==1){ KT=2; NT=8;  off=WOFF_T1; }
  else if (T==2){ KT=4; NT=5;  off=WOFF_T2; }
  else if (T==3){ KT=4; NT=12; off=WOFF_T3; }
  else          { KT=4; NT=4;  off=WOFF_T4; }
  const int f = blockIdx.x*256 + threadIdx.x;
  if (f >= KT*NT*64) return;
  const int lane = f & 63;
  const int fn = f >> 6;
  const int nt = fn % NT, ks = fn / NT;
  const int n  = nt*16 + (lane & 15);
  const int kb = ks*32 + (lane >> 4)*8;
  s16x8 vh, vl;
  #pragma unroll
  for (int i=0;i<8;++i){
    const int k = kb + i;
    float w = 0.f;
    if (T==0){
      if (n < 128)      w = ew1[((size_t)l*130 + k)*128 + n];
      else if (n < 130) w = eresw[((size_t)l*130 + k)*2 + (n-128)];
    } else if (T==1){
      w = n1w1[((size_t)l*66 + k)*128 + n];
    } else if (T==2){
      if (n < 66) w = n1w2[((size_t)l*128 + k)*66 + n];
    } else if (T==3){
      if (n < 128) w = n2w1[((size_t)l*130 + k)*128 + n];
      else         w = n2resw[((size_t)l*130 + k)*64 + (n-128)];
    } else {
      w = n2w2[((size_t)l*128 + k)*64 + n];
    }
    unsigned short hh, rr; split16(w, hh, rr);
    vh[i] = (short)hh; vl[i] = (short)rr;
  }
  *(s16x8*)(wfrag + (size_t)l*WLAYER + off + (size_t)f*8) = vh;
  *(s16x8*)(wfrag + (size_t)l*WLAYER + off + WLO + (size_t)f*8) = vl;
}

// ---------------- init / degree / sort ----------------
__global__ void k_init(const float* __restrict__ x, const float* __restrict__ ea,
                       float* __restrict__ nodes, float* __restrict__ edges,
                       int* __restrict__ cnt,
                       ushort_t* __restrict__ nh, ushort_t* __restrict__ nr){
  const int i = blockIdx.x*256 + threadIdx.x;   // grid = exactly NN*64
  const float v = (i >= NPAD*64) ? x[i - NPAD*64] : 0.f;
  nodes[i] = v;
  if (nh){
    unsigned short us, ur; split16(v, us, ur);
    nh[i] = us; nr[i] = ur;
  }
  if (i < NEDGE*2) edges[i] = ea[i];
  if (i < NN) cnt[i] = 0;
}

__global__ void k_count(const int* __restrict__ ei, int* __restrict__ cnt){
  const int e = blockIdx.x*256 + threadIdx.x;
  if (e < NEDGE) atomicAdd(&cnt[ei[NEDGE + e]], 1);
}

__global__ void k_inv(const int* __restrict__ cnt, float* __restrict__ invc,
                      int* __restrict__ fill){
  const int n = blockIdx.x*256 + threadIdx.x;
  if (n < NN){ invc[n] = 1.0f / (float)max(cnt[n], 1); fill[n] = 0; }
}

__global__ void k_scan(const int* __restrict__ cnt, int* __restrict__ row_start){
  __shared__ int part[256];
  const int t = threadIdx.x;
  int s = 0;
  for (int i=0;i<128;++i) s += cnt[t*128+i];
  part[t] = s;
  __syncthreads();
  if (t == 0){
    int run = 0;
    for (int i=0;i<256;++i){ const int v = part[i]; part[i] = run; run += v; }
  }
  __syncthreads();
  int base = part[t];
  for (int i=0;i<128;++i){ row_start[t*128+i] = base; base += cnt[t*128+i]; }
  if (t == 255) row_start[NN] = base;
}

__global__ void k_place(const int* __restrict__ ei, const int* __restrict__ row_start,
                        int* __restrict__ fill, int* __restrict__ ssrc,
                        int* __restrict__ sdst, int* __restrict__ seid){
  const int e = blockIdx.x*256 + threadIdx.x;
  if (e >= NEDGE) return;
  const int d = ei[NEDGE + e];
  const int pos = row_start[d] + atomicAdd(&fill[d], 1);
  ssrc[pos] = ei[e];
  sdst[pos] = d;
  seid[pos] = e;
}

// deterministic within-bucket order: insertion sort by eid (deg ~7)
__global__ void k_sortb(const int* __restrict__ row_start,
                        int* __restrict__ seid, int* __restrict__ ssrc){
  const int n = blockIdx.x*256 + threadIdx.x;
  if (n >= NN) return;
  const int rs = row_start[n], re = row_start[n+1];
  for (int i = rs+1; i < re; ++i){
    const int e = seid[i], s = ssrc[i];
    int j = i-1;
    while (j >= rs && seid[j] > e){ seid[j+1]=seid[j]; ssrc[j+1]=ssrc[j]; --j; }
    seid[j+1] = e; ssrc[j+1] = s;
  }
}

// permute edge_attr into sorted order (edges stays sorted all layers)
__global__ void k_perm(const float* __restrict__ ea, const int* __restrict__ seid,
                       float* __restrict__ edges){
  const int e = blockIdx.x*256 + threadIdx.x;
  if (e < NEDGE){
    const int o = seid[e];
    ((float2*)edges)[e] = ((const float2*)ea)[o];
  }
}

__global__ void k_zero_agg(float* __restrict__ agg64, float* __restrict__ agg2){
  const int i = blockIdx.x*256 + threadIdx.x;   // grid exactly NN*64
  agg64[i] = 0.f;
  if (i < NN*2) agg2[i] = 0.f;
}

// CSR aggregation: one wave per node, no atomics; eid-ascending order matches
// np.add.at; true fp32 division matches the reference's "/ cnt".
// Emits pre-split f16 hi/res mirrors (split16 of the exact fp32 value).
__global__ __launch_bounds__(256)
void k_agg(const float* __restrict__ medge64, const float* __restrict__ medge2,
           const int* __restrict__ row_start, const int* __restrict__ cnt,
           ushort_t* __restrict__ agg_h, ushort_t* __restrict__ agg_r,
           float* __restrict__ agg2){
  const int n = blockIdx.x*4 + (threadIdx.x >> 6);
  const int lane = threadIdx.x & 63;
  const int rs = row_start[n], re = row_start[n+1];
  const float cf = (float)max(cnt[n], 1);
  float a = 0.f, b = 0.f;
  for (int r = rs; r < re; ++r){
    a = __fadd_rn(a, medge64[(size_t)r*64 + lane]);
    if (lane < 2) b = __fadd_rn(b, medge2[(size_t)r*2 + lane]);
  }
  const float t = a / cf;
  unsigned short th, tr; split16(t, th, tr);
  agg_h[(size_t)n*64 + lane] = th;
  agg_r[(size_t)n*64 + lane] = tr;
  if (lane < 2) agg2[(size_t)n*2 + lane] = b / cf;
}

// ---------------- fused edge kernel (64 edges/block): EdgeModel + mlp_1 ----------------
__global__ __launch_bounds__(256,3)
void k_edge(const int* __restrict__ sidx, const int* __restrict__ didx,
            float* __restrict__ edges,
            const float* __restrict__ nodes,
            const ushort_t* __restrict__ nh, const ushort_t* __restrict__ nr,
            const unsigned short* __restrict__ wf,
            float* __restrict__ agg64, float* __restrict__ agg2,
            float* __restrict__ medge64, float* __restrict__ medge2,
            const float* __restrict__ eb1, const float* __restrict__ ew2,
            const float* __restrict__ eb2, const float* __restrict__ eresb,
            const float* __restrict__ elng, const float* __restrict__ elnb,
            const float* __restrict__ ew1_tail,   // e_w1 rows 128,129 (stride 128)
            const float* __restrict__ eresw_tail, // e_res_w rows 128,129 (stride 2)
            const float* __restrict__ n1w1_tail,  // n1_w1 rows 64,65 (stride 128)
            const float* __restrict__ n1b1, const float* __restrict__ n1b2,
            const float* __restrict__ n1lng, const float* __restrict__ n1lnb)
{
  __shared__ __align__(16) unsigned char sAh[64*128];   // src f16 hi
  __shared__ __align__(16) unsigned char sAl[64*128];   // src f16 scaled-res
  __shared__ __align__(16) unsigned char sBH[64*256];   // dst hi[0:8K) res[8K:16K); later H2 hi (256B rows)
  __shared__ __align__(16) unsigned char sH2l[64*256];  // H2 scaled-res (256B rows)
  __shared__ float sEold[64][2];
  __shared__ int   sCol[64];

  const int tid = threadIdx.x;
  const int ebase = blockIdx.x * 64;

  { // staging: 2 threads per row; tid<128 src, tid>=128 dst
    const int r = (tid & 127) >> 1;
    const int half = tid & 1;
    const int es = ebase + r;
    const int swz = (r & 7) << 4;
    if (tid < 128){
      const int sn = sidx[es];
      if (nh){
        const ushort_t* hp = nh + (size_t)sn*64;
        const ushort_t* rp = nr + (size_t)sn*64;
        #pragma unroll
        for (int cc = 0; cc < 4; ++cc){
          const int c = half*4 + cc;
          const int o = r*128 + ((c*16) ^ swz);
          *(s16x8*)&sAh[o] = *(const s16x8*)(hp + c*8);
          *(s16x8*)&sAl[o] = *(const s16x8*)(rp + c*8);
        }
      } else {
        const float4* sp = (const float4*)(nodes + (size_t)sn*64);
        #pragma unroll
        for (int cc = 0; cc < 4; ++cc){
          const int c = half*4 + cc;
          const float4 f0 = sp[2*c], f1 = sp[2*c+1];
          float v[8] = {f0.x,f0.y,f0.z,f0.w,f1.x,f1.y,f1.z,f1.w};
          s16x8 hh, rr; split8v(v, hh, rr);
          const int o = r*128 + ((c*16) ^ swz);
          *(s16x8*)&sAh[o] = hh;
          *(s16x8*)&sAl[o] = rr;
        }
      }
    } else {
      const int dn = didx[es];
      if (nh){
        const ushort_t* hp = nh + (size_t)dn*64;
        const ushort_t* rp = nr + (size_t)dn*64;
        #pragma unroll
        for (int cc = 0; cc < 4; ++cc){
          const int c = half*4 + cc;
          const int o = r*128 + ((c*16) ^ swz);
          *(s16x8*)&sBH[o] = *(const s16x8*)(hp + c*8);
          *(s16x8*)&sBH[8192 + o] = *(const s16x8*)(rp + c*8);
        }
      } else {
        const float4* dp = (const float4*)(nodes + (size_t)dn*64);
        #pragma unroll
        for (int cc = 0; cc < 4; ++cc){
          const int c = half*4 + cc;
          const float4 f0 = dp[2*c], f1 = dp[2*c+1];
          float v[8] = {f0.x,f0.y,f0.z,f0.w,f1.x,f1.y,f1.z,f1.w};
          s16x8 hh, rr; split8v(v, hh, rr);
          const int o = r*128 + ((c*16) ^ swz);
          *(s16x8*)&sBH[o] = hh;
          *(s16x8*)&sBH[8192 + o] = rr;
        }
      }
      if (half == 0){
        const float2 ev = *(const float2*)(edges + (size_t)es*2);
        sEold[r][0] = ev.x; sEold[r][1] = ev.y;
        sCol[r] = dn;
      }
    }
  }
  __syncthreads();

  const int lane  = tid & 63;
  const int wv    = tid >> 6;
  const int colj  = lane & 15;
  const int g     = lane >> 4;
  const int rowA0 = wv*16 + colj;      // A-frag row
  const int mrow0 = wv*16 + g*4;       // C/D row base (add r)

  float e0r[4], e1r[4];
  #pragma unroll
  for (int r=0; r<4; ++r){
    const int m = mrow0 + r;
    e0r[r] = sEold[m][0]; e1r[r] = sEold[m][1];
  }

  // ---- phase 1: Hext[64,144] = X[64,128] @ W1ext + e-cols fp32 rank-2 ----
  // two nt-halves (5+4) to bound temp-accumulator live range; bitwise same per nt
  f32x4 acc1[9];
  #pragma unroll
  for (int i=0;i<9;++i) acc1[i] = f32x4{0,0,0,0};
  {
    #pragma unroll
    for (int half = 0; half < 2; ++half){
      const int nt0 = half*5;
      const int NTH = half ? 4 : 5;
      f32x4 accR[5];
      #pragma unroll
      for (int i=0;i<5;++i) accR[i] = f32x4{0,0,0,0};
      #pragma unroll
      for (int ks = 0; ks < 4; ++ks){
        const int ch = (ks&1)*4 + g;
        const unsigned char* pH = (ks<2) ? sAh : sBH;
        const unsigned char* pL = (ks<2) ? sAl : (sBH + 8192);
        const int o0 = rowA0*128 + ((ch*16) ^ ((rowA0&7)<<4));
        const f16x8 ah = *(const f16x8*)&pH[o0];
        const f16x8 ar = *(const f16x8*)&pL[o0];
        const f16x8* bh = (const f16x8*)(wf + WOFF_T0) + (ks*9 + nt0)*64 + lane;
        const f16x8* bl = (const f16x8*)(wf + WOFF_T0 + WLO) + (ks*9 + nt0)*64 + lane;
        #pragma unroll
        for (int t = 0; t < 5; ++t){
          if (t >= NTH) break;
          const f16x8 b1 = bh[t*64];
          const f16x8 b2 = bl[t*64];
          acc1[nt0+t] = MFMAH(ah, b1, acc1[nt0+t]);
          accR[t]     = MFMAH(ar, b1, accR[t]);
          accR[t]     = MFMAH(ah, b2, accR[t]);
        }
      }
      #pragma unroll
      for (int t=0; t<5; ++t){
        if (t >= NTH) break;
        #pragma unroll
        for (int r=0; r<4; ++r)
          acc1[nt0+t][r] += accR[t][r] * INV2048;
      }
    }
    #pragma unroll
    for (int nt=0; nt<9; ++nt){
      const int j = nt*16 + colj;
      float w0, w1;
      if (nt < 8){ w0 = ew1_tail[j]; w1 = ew1_tail[128 + j]; }
      else { w0 = (colj<2) ? eresw_tail[colj] : 0.f; w1 = (colj<2) ? eresw_tail[2+colj] : 0.f; }
      #pragma unroll
      for (int r=0; r<4; ++r)
        acc1[nt][r] += e0r[r]*w0 + e1r[r]*w1;
    }
  }

  // ---- phase 2: edge head (N=2) + LN(2) + residual ----
  float enew[4][2];
  {
    float2 w2v[8]; float b1v[8];
    #pragma unroll
    for (int nt=0; nt<8; ++nt){
      const int j = nt*16 + colj;
      w2v[nt] = *(const float2*)(ew2 + (size_t)j*2);
      b1v[nt] = eb1[j];
    }
    const float rb0 = eresb[0], rb1 = eresb[1];
    const float g0 = elng[0], g1 = elng[1], lb0 = elnb[0], lb1 = elnb[1];
    const float bb0 = eb2[0], bb1 = eb2[1];
    #pragma unroll
    for (int r=0; r<4; ++r){
      float v0 = 0.f, v1 = 0.f;
      #pragma unroll
      for (int nt=0; nt<8; ++nt){
        const float h = fmaxf(acc1[nt][r] + b1v[nt], 0.f);
        v0 = fmaf(h, w2v[nt].x, v0);
        v1 = fmaf(h, w2v[nt].y, v1);
      }
      const float resv = acc1[8][r];
      if (colj == 0) v0 += resv + rb0;
      if (colj == 1) v1 += resv + rb1;
      #pragma unroll
      for (int mm=1; mm<16; mm<<=1){
        v0 += __shfl_xor(v0, mm, 64);
        v1 += __shfl_xor(v1, mm, 64);
      }
      v0 += bb0; v1 += bb1;
      // LayerNorm(2) with np-matching rounding
      const float m2 = __fmul_rn(__fadd_rn(v0, v1), 0.5f);
      const float d0 = __fsub_rn(v0, m2);
      const float d1 = __fsub_rn(v1, m2);
      const float var = __fmul_rn(__fadd_rn(__fmul_rn(d0,d0), __fmul_rn(d1,d1)), 0.5f);
      const float rstd = 1.0f / sqrtf(var + 1e-5f);
      const int m = mrow0 + r;
      const float e0 = __fadd_rn(__fadd_rn(__fmul_rn(__fmul_rn(d0, rstd), g0), lb0), e0r[r]);
      const float e1 = __fadd_rn(__fadd_rn(__fmul_rn(__fmul_rn(d1, rstd), g1), lb1), e1r[r]);
      enew[r][0] = e0; enew[r][1] = e1;
      if (colj == 0)
        *(float2*)(edges + (size_t)(ebase + m)*2) = make_float2(e0, e1);
    }
  }

  // ---- phase 3: H2[64,128] = src[64,64] @ n1_w1 (+ fp32 rank-2 for e) ----
  f32x4 acc2[8];
  #pragma unroll
  for (int i=0;i<8;++i) acc2[i] = f32x4{0,0,0,0};
  {
    #pragma unroll
    for (int half = 0; half < 2; ++half){
      const int nt0 = half*4;
      f32x4 accR[4];
      #pragma unroll
      for (int i=0;i<4;++i) accR[i] = f32x4{0,0,0,0};
      #pragma unroll
      for (int ks=0; ks<2; ++ks){
        const int ch = ks*4 + g;
        const int o0 = rowA0*128 + ((ch*16) ^ ((rowA0&7)<<4));
        const f16x8 ah = *(const f16x8*)&sAh[o0];
        const f16x8 ar = *(const f16x8*)&sAl[o0];
        const f16x8* bh = (const f16x8*)(wf + WOFF_T1) + (ks*8 + nt0)*64 + lane;
        const f16x8* bl = (const f16x8*)(wf + WOFF_T1 + WLO) + (ks*8 + nt0)*64 + lane;
        #pragma unroll
        for (int t = 0; t < 4; ++t){
          const f16x8 b1 = bh[t*64];
          const f16x8 b2 = bl[t*64];
          acc2[nt0+t] = MFMAH(ah, b1, acc2[nt0+t]);
          accR[t]     = MFMAH(ar, b1, accR[t]);
          accR[t]     = MFMAH(ah, b2, accR[t]);
        }
      }
      #pragma unroll
      for (int t=0; t<4; ++t)
        #pragma unroll
        for (int r=0; r<4; ++r)
          acc2[nt0+t][r] += accR[t][r] * INV2048;
    }
  }
  {
    #pragma unroll
    for (int nt=0; nt<8; ++nt){
      const int j = nt*16 + colj;
      const float w64 = n1w1_tail[j];
      const float w65 = n1w1_tail[128 + j];
      const float bb = n1b1[j];
      #pragma unroll
      for (int r=0; r<4; ++r){
        float h = acc2[nt][r] + enew[r][0]*w64 + enew[r][1]*w65 + bb;
        acc2[nt][r] = fmaxf(h, 0.f);
      }
    }
  }

  __syncthreads();   // all phase-1 reads of sBH done before overwrite

  // ---- phase 4a: H2 hi -> sBH, H2 lo -> sH2l (single split16) ----
  {
    #pragma unroll
    for (int nt=0; nt<8; ++nt){
      const int j = nt*16 + colj;
      const int co = (j>>3)<<4, wi = (j&7)*2;
      #pragma unroll
      for (int r=0; r<4; ++r){
        const int m = mrow0 + r;
        unsigned short us, ur; split16(acc2[nt][r], us, ur);
        const int o = m*256 + ((co ^ ((m&7)<<4)) + wi);
        *(unsigned short*)&sBH[o]  = us;
        *(unsigned short*)&sH2l[o] = ur;
      }
    }
  }
  __syncthreads();

  // ---- phase 4b: acc3 += H2hi@W1 ; acc3R += H2hi@W2, then += H2lo@W1 ; fold ----
  f32x4 acc3[5], acc3R[5];
  #pragma unroll
  for (int i=0;i<5;++i){ acc3[i] = f32x4{0,0,0,0}; acc3R[i] = f32x4{0,0,0,0}; }
  #pragma unroll
  for (int ks=0; ks<4; ++ks){
    const int ch = ks*4 + g;
    const f16x8 a0 = *(const f16x8*)&sBH[rowA0*256 + ((ch*16) ^ ((rowA0&7)<<4))];
    const f16x8* bh = (const f16x8*)(wf + WOFF_T2) + (ks*5)*64 + lane;
    const f16x8* bl = (const f16x8*)(wf + WOFF_T2 + WLO) + (ks*5)*64 + lane;
    #pragma unroll
    for (int nt = 0; nt < 5; ++nt){
      const f16x8 b1 = bh[nt*64];
      const f16x8 b2 = bl[nt*64];
      acc3[nt]  = MFMAH(a0, b1, acc3[nt]);
      acc3R[nt] = MFMAH(a0, b2, acc3R[nt]);
    }
  }
  #pragma unroll
  for (int ks=0; ks<4; ++ks){
    const int ch = ks*4 + g;
    const f16x8 a0 = *(const f16x8*)&sH2l[rowA0*256 + ((ch*16) ^ ((rowA0&7)<<4))];
    const f16x8* bh = (const f16x8*)(wf + WOFF_T2) + (ks*5)*64 + lane;
    #pragma unroll
    for (int nt = 0; nt < 5; ++nt){
      const f16x8 b1 = bh[nt*64];
      acc3R[nt] = MFMAH(a0, b1, acc3R[nt]);
    }
  }
  #pragma unroll
  for (int nt=0; nt<5; ++nt)
    #pragma unroll
    for (int r=0; r<4; ++r)
      acc3[nt][r] += acc3R[nt][r] * INV2048;

  // ---- phase 4c: LN(66) two-pass (np-matching) + emit ----
  {
    float b2v[5], lgv[5], lbv[5];
    #pragma unroll
    for (int nt=0; nt<5; ++nt){
      const int j = nt*16 + colj;
      const bool ok = j < 66;
      b2v[nt] = ok ? n1b2[j]  : 0.f;
      lgv[nt] = ok ? n1lng[j] : 0.f;
      lbv[nt] = ok ? n1lnb[j] : 0.f;
    }
    #pragma unroll
    for (int r=0; r<4; ++r){
      const int m = mrow0 + r;
      float v[5]; float sum = 0.f;
      #pragma unroll
      for (int nt=0; nt<5; ++nt){
        const int j = nt*16 + colj;
        float xv = 0.f;
        if (j < 64){
          const int o = m*128 + (((((j>>3)<<4)) ^ ((m&7)<<4)) + (j&7)*2);
          const float resd = h2f(*(const unsigned short*)&sAh[o])
                           + h2f(*(const unsigned short*)&sAl[o]) * INV2048;
          xv = __fadd_rn(resd, __fadd_rn(acc3[nt][r], b2v[nt]));
        } else if (j < 66){
          xv = __fadd_rn(enew[r][j-64], __fadd_rn(acc3[nt][r], b2v[nt]));
        }
        v[nt] = xv;
        sum += xv;
      }
      #pragma unroll
      for (int mm=1; mm<16; mm<<=1) sum += __shfl_xor(sum, mm, 64);
      const float mean = sum / 66.0f;
      float d[5]; float sq = 0.f;
      #pragma unroll
      for (int nt=0; nt<5; ++nt){
        const int j = nt*16 + colj;
        d[nt] = (j < 66) ? __fsub_rn(v[nt], mean) : 0.f;
        sq = __fadd_rn(sq, __fmul_rn(d[nt], d[nt]));
      }
      #pragma unroll
      for (int mm=1; mm<16; mm<<=1) sq += __shfl_xor(sq, mm, 64);
      const float var  = sq / 66.0f;
      const float rstd = 1.0f / sqrtf(var + 1e-5f);
      if (medge64){
        float* m64 = medge64 + (size_t)(ebase + m)*64;
        #pragma unroll
        for (int nt=0; nt<4; ++nt)
          m64[nt*16 + colj] = __fadd_rn(__fmul_rn(__fmul_rn(d[nt], rstd), lgv[nt]), lbv[nt]);
        if (colj < 2)
          medge2[(size_t)(ebase + m)*2 + colj] =
            __fadd_rn(__fmul_rn(__fmul_rn(d[4], rstd), lgv[4]), lbv[4]);
      } else {
        float* a64 = agg64 + (size_t)sCol[m]*64;
        #pragma unroll
        for (int nt=0; nt<4; ++nt)
          atomicAdd(a64 + nt*16 + colj, __fadd_rn(__fmul_rn(__fmul_rn(d[nt], rstd), lgv[nt]), lbv[nt]));
        if (colj < 2)
          atomicAdd(agg2 + (size_t)sCol[m]*2 + colj,
                    __fadd_rn(__fmul_rn(__fmul_rn(d[4], rstd), lgv[4]), lbv[4]));
      }
    }
  }
}

// ---------------- node kernel (64 nodes/block): NodeModel.mlp_2 ----------------
__global__ __launch_bounds__(256,3)
void k_node(float* __restrict__ nodes,
            ushort_t* __restrict__ nh, ushort_t* __restrict__ nr,
            const float* __restrict__ agg64,
            const ushort_t* __restrict__ agg_h, const ushort_t* __restrict__ agg_r,
            const float* __restrict__ agg2,
            const float* __restrict__ invc,
            const unsigned short* __restrict__ wf,
            const float* __restrict__ b1, const float* __restrict__ resb,
            const float* __restrict__ b2, const float* __restrict__ lng,
            const float* __restrict__ lnb,
            const float* __restrict__ n2w1_tail,   // n2_w1 rows 128,129 (stride 128)
            const float* __restrict__ n2resw_tail) // n2_res_w rows 128,129 (stride 64)
{
  __shared__ __align__(16) unsigned char sAh[64*128];   // nodes f16 hi
  __shared__ __align__(16) unsigned char sAl[64*128];   // nodes f16 scaled-res
  __shared__ __align__(16) unsigned char sBH[64*256];   // agg hi/res; later H3 hi (256B rows)
  __shared__ __align__(16) unsigned char sH3l[64*256];  // H3 scaled-res (256B rows)
  __shared__ float sAgg2[64][2];

  const int tid = threadIdx.x;
  const int nbase = blockIdx.x * 64;

  { // staging: 2 threads per row
    const int r = (tid & 127) >> 1;
    const int half = tid & 1;
    const int node = nbase + r;
    const int swz = (r & 7) << 4;
    if (tid < 128){
      if (nh){
        const ushort_t* hp = nh + (size_t)node*64;
        const ushort_t* rp = nr + (size_t)node*64;
        #pragma unroll
        for (int cc = 0; cc < 4; ++cc){
          const int c = half*4 + cc;
          const int o = r*128 + ((c*16) ^ swz);
          *(s16x8*)&sAh[o] = *(const s16x8*)(hp + c*8);
          *(s16x8*)&sAl[o] = *(const s16x8*)(rp + c*8);
        }
      } else {
        const float4* sp = (const float4*)(nodes + (size_t)node*64);
        #pragma unroll
        for (int cc = 0; cc < 4; ++cc){
          const int c = half*4 + cc;
          const float4 f0 = sp[2*c], f1 = sp[2*c+1];
          float v[8] = {f0.x,f0.y,f0.z,f0.w,f1.x,f1.y,f1.z,f1.w};
          s16x8 hh, rr; split8v(v, hh, rr);
          const int o = r*128 + ((c*16) ^ swz);
          *(s16x8*)&sAh[o] = hh;
          *(s16x8*)&sAl[o] = rr;
        }
      }
    } else {
      if (agg_h){
        const ushort_t* hp = agg_h + (size_t)node*64;
        const ushort_t* rp = agg_r + (size_t)node*64;
        #pragma unroll
        for (int cc = 0; cc < 4; ++cc){
          const int c = half*4 + cc;
          const int o = r*128 + ((c*16) ^ swz);
          *(s16x8*)&sBH[o] = *(const s16x8*)(hp + c*8);
          *(s16x8*)&sBH[8192 + o] = *(const s16x8*)(rp + c*8);
        }
        if (half == 0){
          sAgg2[r][0] = agg2[(size_t)node*2];
          sAgg2[r][1] = agg2[(size_t)node*2+1];
        }
      } else {
        const float iv = invc[node];
        const float* a64 = agg64 + (size_t)node*64;
        #pragma unroll
        for (int cc = 0; cc < 4; ++cc){
          const int c = half*4 + cc;
          float v[8];
          #pragma unroll
          for (int i=0;i<8;++i) v[i] = a64[c*8+i]*iv;
          s16x8 hh, rr; split8v(v, hh, rr);
          const int o = r*128 + ((c*16) ^ swz);
          *(s16x8*)&sBH[o] = hh;
          *(s16x8*)&sBH[8192 + o] = rr;
        }
        if (half == 0){
          sAgg2[r][0] = agg2[(size_t)node*2]*iv;
          sAgg2[r][1] = agg2[(size_t)node*2+1]*iv;
        }
      }
    }
  }
  __syncthreads();

  const int lane  = tid & 63;
  const int wv    = tid >> 6;
  const int colj  = lane & 15;
  const int g     = lane >> 4;
  const int rowA0 = wv*16 + colj;
  const int mrow0 = wv*16 + g*4;

  float a0r[4], a1r[4];
  #pragma unroll
  for (int r=0; r<4; ++r){
    const int m = mrow0 + r;
    a0r[r] = sAgg2[m][0]; a1r[r] = sAgg2[m][1];
  }

  // ---- GEMM1: [64,128] @ W1ext -> [64,192] in two nt-halves ----
  f32x4 acc1[12];
  #pragma unroll
  for (int i=0;i<12;++i) acc1[i] = f32x4{0,0,0,0};
  #pragma unroll
  for (int half = 0; half < 2; ++half){
    f32x4 aR[6];
    #pragma unroll
    for (int i=0;i<6;++i) aR[i] = f32x4{0,0,0,0};
    #pragma unroll
    for (int ks = 0; ks < 4; ++ks){
      const int ch = (ks&1)*4 + g;
      const unsigned char* pH = (ks<2) ? sAh : sBH;
      const unsigned char* pL = (ks<2) ? sAl : (sBH + 8192);
      const int o0 = rowA0*128 + ((ch*16) ^ ((rowA0&7)<<4));
      const f16x8 ah = *(const f16x8*)&pH[o0];
      const f16x8 ar = *(const f16x8*)&pL[o0];
      const f16x8* bh = (const f16x8*)(wf + WOFF_T3) + (ks*12 + half*6)*64 + lane;
      const f16x8* bl = (const f16x8*)(wf + WOFF_T3 + WLO) + (ks*12 + half*6)*64 + lane;
      #pragma unroll
      for (int t = 0; t < 6; ++t){
        const int nt = half*6 + t;
        const f16x8 b1 = bh[t*64];
        const f16x8 b2 = bl[t*64];
        acc1[nt] = MFMAH(ah, b1, acc1[nt]);
        aR[t]    = MFMAH(ar, b1, aR[t]);
        aR[t]    = MFMAH(ah, b2, aR[t]);
      }
    }
    #pragma unroll
    for (int t=0;t<6;++t)
      #pragma unroll
      for (int r=0; r<4; ++r)
        acc1[half*6+t][r] += aR[t][r] * INV2048;
  }
  { // agg cols 64,65 (W rows 128,129) exact fp32
    #pragma unroll
    for (int nt=0; nt<12; ++nt){
      const int j = nt*16 + colj;
      float w0, w1;
      if (j < 128){ w0 = n2w1_tail[j]; w1 = n2w1_tail[128 + j]; }
      else { w0 = n2resw_tail[j-128]; w1 = n2resw_tail[64 + (j-128)]; }
      #pragma unroll
      for (int r=0; r<4; ++r)
        acc1[nt][r] += a0r[r]*w0 + a1r[r]*w1;
    }
  }
  { // fold bias+relu into acc1 hidden part
    #pragma unroll
    for (int nt=0; nt<8; ++nt){
      const float bb = b1[nt*16 + colj];
      #pragma unroll
      for (int r=0; r<4; ++r)
        acc1[nt][r] = fmaxf(acc1[nt][r] + bb, 0.f);
    }
  }

  __syncthreads();   // all reads of sBH done before overwrite with H3

  { // H3 hi -> sBH, lo -> sH3l (single split16)
    #pragma unroll
    for (int nt=0; nt<8; ++nt){
      const int j = nt*16 + colj;
      const int co = (j>>3)<<4, wi = (j&7)*2;
      #pragma unroll
      for (int r=0; r<4; ++r){
        const int m = mrow0 + r;
        unsigned short us, ur; split16(acc1[nt][r], us, ur);
        const int o = m*256 + ((co ^ ((m&7)<<4)) + wi);
        *(unsigned short*)&sBH[o]  = us;
        *(unsigned short*)&sH3l[o] = ur;
      }
    }
  }
  __syncthreads();

  // ---- GEMM2: acc2 += H3hi@W1 ; acc2R += H3hi@W2, then += H3lo@W1 ; fold ----
  f32x4 acc2[4], acc2R[4];
  #pragma unroll
  for (int i=0;i<4;++i){ acc2[i] = f32x4{0,0,0,0}; acc2R[i] = f32x4{0,0,0,0}; }
  #pragma unroll
  for (int ks=0; ks<4; ++ks){
    const int ch = ks*4 + g;
    const f16x8 a0 = *(const f16x8*)&sBH[rowA0*256 + ((ch*16) ^ ((rowA0&7)<<4))];
    const f16x8* bh = (const f16x8*)(wf + WOFF_T4) + (ks*4)*64 + lane;
    const f16x8* bl = (const f16x8*)(wf + WOFF_T4 + WLO) + (ks*4)*64 + lane;
    #pragma unroll
    for (int nt = 0; nt < 4; ++nt){
      const f16x8 b1 = bh[nt*64];
      const f16x8 b2 = bl[nt*64];
      acc2[nt]  = MFMAH(a0, b1, acc2[nt]);
      acc2R[nt] = MFMAH(a0, b2, acc2R[nt]);
    }
  }
  #pragma unroll
  for (int ks=0; ks<4; ++ks){
    const int ch = ks*4 + g;
    const f16x8 a0 = *(const f16x8*)&sH3l[rowA0*256 + ((ch*16) ^ ((rowA0&7)<<4))];
    const f16x8* bh = (const f16x8*)(wf + WOFF_T4) + (ks*4)*64 + lane;
    #pragma unroll
    for (int nt = 0; nt < 4; ++nt){
      const f16x8 b1 = bh[nt*64];
      acc2R[nt] = MFMAH(a0, b1, acc2R[nt]);
    }
  }
  #pragma unroll
  for (int nt=0; nt<4; ++nt)
    #pragma unroll
    for (int r=0; r<4; ++r)
      acc2[nt][r] += acc2R[nt][r] * INV2048;

  // ---- epilogue: LN(64) two-pass (np-matching) + residual + "+nodes" ----
  {
    float b2v[4], rbv[4], lgv[4], lbv[4];
    #pragma unroll
    for (int nt=0; nt<4; ++nt){
      const int j = nt*16 + colj;
      b2v[nt] = b2[j]; rbv[nt] = resb[j]; lgv[nt] = lng[j]; lbv[nt] = lnb[j];
    }
    #pragma unroll
    for (int r=0; r<4; ++r){
      const int m = mrow0 + r;
      const int node = nbase + m;
      float v[4]; float sum = 0.f;
      #pragma unroll
      for (int nt=0; nt<4; ++nt){
        const float resi = __fadd_rn(acc1[8+nt][r], rbv[nt]);
        const float hh   = __fadd_rn(acc2[nt][r], b2v[nt]);
        const float xv = __fadd_rn(resi, hh);
        v[nt] = xv; sum += xv;
      }
      #pragma unroll
      for (int mm=1; mm<16; mm<<=1) sum += __shfl_xor(sum, mm, 64);
      const float mean = sum / 64.0f;
      float d[4]; float sq = 0.f;
      #pragma unroll
      for (int nt=0; nt<4; ++nt){
        d[nt] = __fsub_rn(v[nt], mean);
        sq = __fadd_rn(sq, __fmul_rn(d[nt], d[nt]));
      }
      #pragma unroll
      for (int mm=1; mm<16; mm<<=1) sq += __shfl_xor(sq, mm, 64);
      const float var  = sq / 64.0f;
      const float rstd = 1.0f / sqrtf(var + 1e-5f);
      #pragma unroll
      for (int nt=0; nt<4; ++nt){
        const int j = nt*16 + colj;
        const size_t idx = (size_t)node*64 + j;
        const float lnout = __fadd_rn(__fmul_rn(__fmul_rn(d[nt], rstd), lgv[nt]), lbv[nt]);
        const float out = __fadd_rn(lnout, nodes[idx]);
        nodes[idx] = out;
        if (nh){
          unsigned short us, ur; split16(out, us, ur);
          nh[idx] = us; nr[idx] = ur;
        }
      }
    }
  }
}

__global__ void k_copy(const float* __restrict__ nodes, float* __restrict__ out){
  const int i = blockIdx.x*256 + threadIdx.x;   // grid exactly NACT*16
  if (i < NACT*16)
    ((float4*)out)[i] = ((const float4*)nodes)[NPAD*16 + i];
}

extern "C" void kernel_launch(void* const* d_in, const int* in_sizes, int n_in,
                              void* d_out, int out_size, void* d_ws, size_t ws_size,
                              hipStream_t stream){
  const float* x       = (const float*)d_in[0];
  const int*   ei      = (const int*)  d_in[1];
  const float* eattr   = (const float*)d_in[2];
  const float* e_res_w = (const float*)d_in[3];
  const float* e_res_b = (const float*)d_in[4];
  const float* e_w1    = (const float*)d_in[5];
  const float* e_b1    = (const float*)d_in[6];
  const float* e_w2    = (const float*)d_in[7];
  const float* e_b2    = (const float*)d_in[8];
  const float* e_ln_g  = (const float*)d_in[9];
  const float* e_ln_b  = (const float*)d_in[10];
  const float* n1_w1   = (const float*)d_in[11];
  const float* n1_b1   = (const float*)d_in[12];
  const float* n1_w2   = (const float*)d_in[13];
  const float* n1_b2   = (const float*)d_in[14];
  const float* n1_ln_g = (const float*)d_in[15];
  const float* n1_ln_b = (const float*)d_in[16];
  const float* n2_res_w= (const float*)d_in[17];
  const float* n2_res_b= (const float*)d_in[18];
  const float* n2_w1   = (const float*)d_in[19];
  const float* n2_b1   = (const float*)d_in[20];
  const float* n2_w2   = (const float*)d_in[21];
  const float* n2_b2   = (const float*)d_in[22];
  const float* n2_ln_g = (const float*)d_in[23];
  const float* n2_ln_b = (const float*)d_in[24];

  if (ws_size < 21364736u) return;

  char* ws = (char*)d_ws;
  float*          nodes = (float*)(ws + 0);             // NN*64 f32
  float*          edges = (float*)(ws + 8388608);       // NEDGE*2 f32
  float*          agg64 = (float*)(ws + 10223616);      // NN*64 f32 (slow path) / mirrors (fast)
  ushort_t*       agg_h = (ushort_t*)(ws + 10223616);   // NN*64 u16 (overlays agg64)
  ushort_t*       agg_r = (ushort_t*)(ws + 14417920);   // NN*64 u16
  float*          agg2  = (float*)(ws + 18612224);      // NN*2 f32
  int*            cnt   = (int*)(ws + 18874368);
  float*          invc  = (float*)(ws + 19005440);
  unsigned short* wfrag = (unsigned short*)(ws + 19136512);  // ends 21364736
  // fast-path extras
  int*   row_start = (int*)(ws + 21364736);             // NN+1 ints
  int*   fill      = (int*)(ws + 21496064);
  int*   ssrc      = (int*)(ws + 21627136);
  int*   sdst      = (int*)(ws + 22544640);
  int*   seid      = (int*)(ws + 23462144);
  float* medge64   = (float*)(ws + 24379648);           // NEDGE*64 f32
  float* medge2    = (float*)(ws + 83099904);           // NEDGE*2 f32, ends 84934912
  ushort_t* nodes_h = (ushort_t*)(ws + 84934912);       // NN*64 u16
  ushort_t* nodes_r = (ushort_t*)(ws + 89129216);       // NN*64 u16, ends 93323520

  const bool fast  = ws_size >= 84934912u;
  const bool fast2 = ws_size >= 93323520u;

  ushort_t* nh = fast2 ? nodes_h : nullptr;
  ushort_t* nr = fast2 ? nodes_r : nullptr;

  k_pack<<<dim3(12,8,5),256,0,stream>>>(e_w1, e_res_w, n1_w1, n1_w2, n2_w1, n2_res_w, n2_w2, wfrag);
  k_init<<<8192,256,0,stream>>>(x, eattr, nodes, edges, cnt, nh, nr);
  k_count<<<896,256,0,stream>>>(ei, cnt);
  k_inv<<<128,256,0,stream>>>(cnt, invc, fast ? fill : cnt /*dummy*/);

  const int* sidx = ei;
  const int* didx = ei + NEDGE;
  if (fast){
    k_scan<<<1,256,0,stream>>>(cnt, row_start);
    k_place<<<896,256,0,stream>>>(ei, row_start, fill, ssrc, sdst, seid);
    k_sortb<<<128,256,0,stream>>>(row_start, seid, ssrc);
    k_perm<<<896,256,0,stream>>>(eattr, seid, edges);
    sidx = ssrc; didx = sdst;
  }

  for (int l = 0; l < NLAY; ++l){
    if (!fast) k_zero_agg<<<8192,256,0,stream>>>(agg64, agg2);
    k_edge<<<3584,256,0,stream>>>(sidx, didx, edges, nodes, nh, nr,
        wfrag + (size_t)l*WLAYER, agg64, agg2,
        fast ? medge64 : nullptr, fast ? medge2 : nullptr,
        e_b1 + l*128, e_w2 + l*256, e_b2 + l*2, e_res_b + l*2, e_ln_g + l*2, e_ln_b + l*2,
        e_w1 + ((size_t)l*130 + 128)*128,
        e_res_w + ((size_t)l*130 + 128)*2,
        n1_w1 + ((size_t)l*66 + 64)*128,
        n1_b1 + l*128, n1_b2 + l*66, n1_ln_g + l*66, n1_ln_b + l*66);
    if (fast) k_agg<<<8192,256,0,stream>>>(medge64, medge2, row_start, cnt, agg_h, agg_r, agg2);
    k_node<<<512,256,0,stream>>>(nodes, nh, nr,
        fast ? nullptr : agg64,
        fast ? agg_h : nullptr, fast ? agg_r : nullptr, agg2,
        fast ? nullptr : invc,
        wfrag + (size_t)l*WLAYER,
        n2_b1 + l*128, n2_res_b + l*64, n2_b2 + l*64, n2_ln_g + l*64, n2_ln_b + l*64,
        n2_w1 + ((size_t)l*130 + 128)*128,
        n2_res_w + ((size_t)l*130 + 128)*64);
  }
  k_copy<<<1792,256,0,stream>>>(nodes, (float*)d_out);
}